// Round 10
// baseline (158.161 us; speedup 1.0000x reference)
//
#include <hip/hip_runtime.h>
#include <stdint.h>

// B=32, C=256, H=W=32 (HW=1024), GROUPS=32, EPS=1e-5.
// K0 wprep : Wt[d][c] bf16 (gs/scale folded), bias folded. q-scale = log2e/16.
// K1 gn    : Xh[b][p][c] bf16.
// K2 gemm<0>: Q,K proj -> FP8 e4m3 [p][d], cols interleaved (d = n0+lr*4+nt).
//    gemm<1>: V proj -> FP8 [c][p].
//    gemm<2>: final out = x + Wo^T O + bo (fp32).
// K3 attn  : full-FP8 flash attn, mfma_f32_32x32x16_fp8_fp8.
//            2-WAVE blocks (128 thr), grid 512 -> 4 blocks/CU, 2 waves/SIMD.
//            K/V LDS dbuf 32KB; 1 barrier/step; lane-local defer-max softmax;
//            P packed to fp8 in-register (4 shfl).

#define NB 32
#define CH 256
#define HWPX 1024

typedef __bf16 bf16x8 __attribute__((ext_vector_type(8)));
typedef float f32x4 __attribute__((ext_vector_type(4)));
typedef float f32x16 __attribute__((ext_vector_type(16)));
typedef unsigned short u16;
typedef unsigned char u8;
typedef unsigned int u32;
typedef u16 u16x8 __attribute__((ext_vector_type(8)));
typedef u32 u32x2 __attribute__((ext_vector_type(2)));

__device__ __forceinline__ u16 f2bf(float f) {
    __bf16 h = (__bf16)f;
    return __builtin_bit_cast(u16, h);
}
__device__ __forceinline__ bf16x8 ldb8(const u16* p) {
    return __builtin_bit_cast(bf16x8, *(const u16x8*)p);
}
__device__ __forceinline__ u32 pkfp8(float a, float b, float c, float d) {
    int w = __builtin_amdgcn_cvt_pk_fp8_f32(a, b, 0, false);
    w = __builtin_amdgcn_cvt_pk_fp8_f32(c, d, w, true);
    return (u32)w;
}
__device__ __forceinline__ void gld_lds16(const u8* g, u8* l) {
    __builtin_amdgcn_global_load_lds(
        (const __attribute__((address_space(1))) void*)g,
        (__attribute__((address_space(3))) void*)l, 16, 0, 0);
}

// ---------------- K0: weight prep ----------------
__global__ __launch_bounds__(256) void wprep(
    const float* __restrict__ Wq, const float* __restrict__ bq,
    const float* __restrict__ gqs, const float* __restrict__ gqb,
    const float* __restrict__ Wk, const float* __restrict__ bk,
    const float* __restrict__ gks, const float* __restrict__ gkb,
    const float* __restrict__ Wv, const float* __restrict__ bv,
    const float* __restrict__ gvs, const float* __restrict__ gvb,
    const float* __restrict__ Wo, const float* __restrict__ bo,
    u16* __restrict__ Wt, float* __restrict__ bias)
{
    int m = blockIdx.x >> 8;
    int d = blockIdx.x & 255;
    int c = threadIdx.x;
    const float *W, *bb, *gs, *gb; float scale;
    const float QSC = 0.09016844005556021f;   // log2(e)/16
    if (m == 0)      { W = Wq; bb = bq; gs = gqs; gb = gqb; scale = QSC; }
    else if (m == 1) { W = Wk; bb = bk; gs = gks; gb = gkb; scale = 1.f; }
    else if (m == 2) { W = Wv; bb = bv; gs = gvs; gb = gvb; scale = 1.f; }
    else             { W = Wo; bb = bo; gs = nullptr; gb = nullptr; scale = 1.f; }
    float w   = W[c * 256 + d];
    float gsc = gs ? gs[c] : 1.f;
    float gbc = gb ? gb[c] : 0.f;
    Wt[((size_t)m << 16) + d * 256 + c] = f2bf(w * gsc * scale);
    __shared__ float red[256];
    red[c] = gbc * w;
    __syncthreads();
    for (int s = 128; s > 0; s >>= 1) { if (c < s) red[c] += red[c + s]; __syncthreads(); }
    if (c == 0) bias[m * 256 + d] = (bb[d] + red[0]) * scale;
}

// ---------------- K1: groupnorm ----------------
__global__ __launch_bounds__(256) void gn_kernel(const float* __restrict__ x,
                                                 u16* __restrict__ Xh)
{
    int blk = blockIdx.x;
    int b = blk >> 5, g = blk & 31;
    const float* base = x + (size_t)(b * 256 + g * 8) * 1024;
    int t = threadIdx.x;
    float s = 0.f, s2 = 0.f;
    for (int i = 0; i < 32; i++) { float v = base[t + i * 256]; s += v; s2 += v * v; }
    __shared__ float rs[256], rq[256];
    rs[t] = s; rq[t] = s2;
    __syncthreads();
    for (int k = 128; k > 0; k >>= 1) {
        if (t < k) { rs[t] += rs[t + k]; rq[t] += rq[t + k]; }
        __syncthreads();
    }
    float mu  = rs[0] * (1.f / 8192.f);
    float var = rq[0] * (1.f / 8192.f) - mu * mu;
    float rv  = rsqrtf(var + 1e-5f);
    u16* outp = Xh + (size_t)b * (HWPX * CH) + g * 8;
    for (int it = 0; it < 4; it++) {
        int p = t + it * 256;
        u16x8 tv;
        #pragma unroll
        for (int c2 = 0; c2 < 8; c2++) tv[c2] = f2bf((base[c2 * 1024 + p] - mu) * rv);
        *(u16x8*)(outp + (size_t)p * 256) = tv;
    }
}

// ---------------- K2/K4: NT GEMM, shared B-tile in LDS ----------------
// MODE0: fp8 out [m][256], col = n0 + lr*4 + nt (interleaved), dword stores.
// MODE1: fp8 out Vc[b][m][p], natural cols, byte stores.
// MODE2: fp32 out + residual.
template <int MODE>
__global__ __launch_bounds__(256) void gemm_nt(
    const u16* __restrict__ A, const u16* __restrict__ Bm,
    const float* __restrict__ bias,
    u8* __restrict__ C8, float* __restrict__ Cf,
    const float* __restrict__ xres)
{
    __shared__ __align__(16) u16 Bt[64 * 256];
    int tid = threadIdx.x;
    int lane = tid & 63, wave = tid >> 6;
    int m0 = blockIdx.y * 64 + wave * 16;
    int n0 = blockIdx.x * 64;

    #pragma unroll
    for (int i = 0; i < 8; i++) {
        int G = i * 256 + tid;
        int row = G >> 5, g = G & 31;
        const u16* src = Bm + (size_t)(n0 + row) * 256 + ((g ^ (row & 7)) << 3);
        gld_lds16((const u8*)src, (u8*)(Bt + (size_t)(i * 256 + wave * 64) * 8));
    }

    int lr = lane & 15, hk = lane >> 4, lk = hk * 8;
    const u16* Ap = A + (size_t)(m0 + lr) * 256 + lk;
    bf16x8 af[8];
    #pragma unroll
    for (int kk = 0; kk < 8; kk++) af[kk] = ldb8(Ap + kk * 32);

    __syncthreads();

    f32x4 acc[4] = {};
    #pragma unroll
    for (int kk = 0; kk < 8; kk++) {
        #pragma unroll
        for (int nt = 0; nt < 4; nt++) {
            int row = (MODE == 0) ? (lr * 4 + nt) : (nt * 16 + lr);
            int g = (kk * 4 + hk) ^ (row & 7);
            bf16x8 bf = ldb8(Bt + (size_t)(row * 32 + g) * 8);
            acc[nt] = __builtin_amdgcn_mfma_f32_16x16x32_bf16(af[kk], bf, acc[nt], 0, 0, 0);
        }
    }
    int rbase = m0 + (hk << 2);
    if (MODE == 0) {
        int colbase = n0 + lr * 4;
        #pragma unroll
        for (int j = 0; j < 4; j++) {
            int row = rbase + j;
            u32 w = pkfp8(acc[0][j] + bias[colbase],
                          acc[1][j] + bias[colbase + 1],
                          acc[2][j] + bias[colbase + 2],
                          acc[3][j] + bias[colbase + 3]);
            *(u32*)(C8 + (size_t)row * 256 + colbase) = w;
        }
    } else {
        #pragma unroll
        for (int nt = 0; nt < 4; nt++) {
            int col = n0 + nt * 16 + lr;
            int b = col >> 10, p = col & 1023;
            #pragma unroll
            for (int j = 0; j < 4; j++) {
                int row = rbase + j;
                float v = acc[nt][j] + bias[row];
                size_t off = (size_t)b * (CH * HWPX) + (size_t)row * 1024 + p;
                if (MODE == 1) {
                    int w = __builtin_amdgcn_cvt_pk_fp8_f32(v, v, 0, false);
                    C8[off] = (u8)(w & 0xff);
                } else {
                    Cf[off] = v + xres[off];
                }
            }
        }
    }
}

// ---------------- K3: full-FP8 flash attention, 2-wave blocks ----------------
// grid 512 (4 blocks/CU, 2 waves/SIMD), 2 waves x 32 q-rows, KV step 32, 32 steps.
// S^T = mfma(K, Q); lane owns q = q0+(lane&31); P packed to fp8 in-register.
__global__ __launch_bounds__(128, 2) void attn(
    const u8* __restrict__ Qf8, const u8* __restrict__ Kf8,
    const u8* __restrict__ Vf8, u16* __restrict__ O)
{
    __shared__ __align__(16) u8 Kbuf[2][32 * 256];   // 2 x 8 KB, granule(16B) ^= row&7
    __shared__ __align__(16) u8 Vbuf[2][256 * 32];   // 2 x 8 KB, granule ^= (c>>2)&1

    int tid = threadIdx.x;
    int lane = tid & 63, wave = tid >> 6;
    int bid = blockIdx.x;
    // XCD x hosts batches 4x..4x+3; a batch's 16 blocks co-located on one XCD
    int xcd = bid & 7, local = bid >> 3;      // local 0..63
    int b  = xcd * 4 + (local >> 4);
    int qb = local & 15;
    int q0 = qb * 64 + wave * 32;

    const u8* Qb = Qf8 + (size_t)b * (HWPX * CH);
    const u8* Kb = Kf8 + (size_t)b * (HWPX * CH);
    const u8* Vb = Vf8 + (size_t)b * (CH * HWPX);

    int lq = lane & 31, hi = lane >> 5;
    int kswz = lq & 7;
    int vs1  = (lq >> 2) & 1;

    // staging source offsets (inverse-swizzled, LDS dest linear); 4 insts per buffer
    int koff[4], voff[4];
    #pragma unroll
    for (int i = 0; i < 4; i++) {
        int G = i * 128 + tid;
        int kr = G >> 4, kg = G & 15;
        koff[i] = kr * 256 + ((kg ^ (kr & 7)) << 4);
        int vr = G >> 1, vg = G & 1;
        voff[i] = vr * 1024 + ((vg ^ ((vr >> 2) & 1)) << 4);
    }

    // Q fragments: qf[f] = Q[q0+lq][f*16 + hi*8 .. +7] (fp8, 8 bytes)
    long qf[16];
    #pragma unroll
    for (int f = 0; f < 16; f++)
        qf[f] = *(const long*)(Qb + (size_t)(q0 + lq) * 256 + f * 16 + hi * 8);

    f32x16 oa[8] = {};
    float m_run = -1e30f, l_run = 0.f;

    // prologue: stage tile 0
    #pragma unroll
    for (int i = 0; i < 4; i++)
        gld_lds16(Kb + koff[i], &Kbuf[0][0] + (size_t)(i * 128 + wave * 64) * 16);
    #pragma unroll
    for (int i = 0; i < 4; i++)
        gld_lds16(Vb + voff[i], &Vbuf[0][0] + (size_t)(i * 128 + wave * 64) * 16);
    __syncthreads();

    for (int t = 0; t < 32; ++t) {
        int cur = t & 1;
        if (t < 31) {
            const u8* ks = Kb + (size_t)(t + 1) * (32 * 256);
            const u8* vs = Vb + (t + 1) * 32;
            #pragma unroll
            for (int i = 0; i < 4; i++)
                gld_lds16(ks + koff[i], &Kbuf[cur ^ 1][0] + (size_t)(i * 128 + wave * 64) * 16);
            #pragma unroll
            for (int i = 0; i < 4; i++)
                gld_lds16(vs + voff[i], &Vbuf[cur ^ 1][0] + (size_t)(i * 128 + wave * 64) * 16);
        }

        // ---- QK^T (fp8): S^T tile 32kv x 32q, two accumulators ----
        const u8* kb = Kbuf[cur];
        f32x16 s0 = {}, s1 = {};
        #pragma unroll
        for (int ff = 0; ff < 8; ff++) {
            long k0 = *(const long*)(kb + (size_t)lq * 256 + (((2 * ff) ^ kswz) << 4) + hi * 8);
            s0 = __builtin_amdgcn_mfma_f32_32x32x16_fp8_fp8(k0, qf[2 * ff], s0, 0, 0, 0);
            long k1 = *(const long*)(kb + (size_t)lq * 256 + (((2 * ff + 1) ^ kswz) << 4) + hi * 8);
            s1 = __builtin_amdgcn_mfma_f32_32x32x16_fp8_fp8(k1, qf[2 * ff + 1], s1, 0, 0, 0);
        }
        float s[16];
        #pragma unroll
        for (int r = 0; r < 16; r++) s[r] = s0[r] + s1[r];

        // ---- lane-local defer-max softmax (log2 domain) ----
        float m01 = fmaxf(s[0], s[1]),   m23 = fmaxf(s[2], s[3]);
        float m45 = fmaxf(s[4], s[5]),   m67 = fmaxf(s[6], s[7]);
        float m89 = fmaxf(s[8], s[9]),   mab = fmaxf(s[10], s[11]);
        float mcd = fmaxf(s[12], s[13]), mef = fmaxf(s[14], s[15]);
        float mloc = fmaxf(fmaxf(fmaxf(m01, m23), fmaxf(m45, m67)),
                           fmaxf(fmaxf(m89, mab), fmaxf(mcd, mef)));
        if (!__all(mloc - m_run <= 4.f)) {          // rare: t==0 or max jumped
            float mo = fmaxf(mloc, __shfl_xor(mloc, 32));
            float mn = fmaxf(m_run, mo);
            float sc = exp2f(m_run - mn);
            m_run = mn;
            l_run *= sc;
            #pragma unroll
            for (int ct = 0; ct < 8; ct++) {
                #pragma unroll
                for (int r = 0; r < 16; r++) oa[ct][r] *= sc;
            }
        }
        float p[16];
        #pragma unroll
        for (int r = 0; r < 16; r++) p[r] = exp2f(s[r] - m_run);   // <= 2^4
        l_run += (((p[0]+p[1])+(p[2]+p[3]))+((p[4]+p[5])+(p[6]+p[7])))
               + (((p[8]+p[9])+(p[10]+p[11]))+((p[12]+p[13])+(p[14]+p[15])));

        // ---- pack P^T to fp8 B-fragments in-register ----
        u32 a  = pkfp8(p[0],  p[1],  p[2],  p[3]);
        u32 bb = pkfp8(p[4],  p[5],  p[6],  p[7]);
        u32 c  = pkfp8(p[8],  p[9],  p[10], p[11]);
        u32 d  = pkfp8(p[12], p[13], p[14], p[15]);
        u32 xa = (u32)__shfl_xor((int)a, 32),  xb = (u32)__shfl_xor((int)bb, 32);
        u32 xc = (u32)__shfl_xor((int)c, 32),  xd = (u32)__shfl_xor((int)d, 32);
        u32x2 f0 = { hi ? xb : a, hi ? bb : xa };
        u32x2 f1 = { hi ? xd : c, hi ? d  : xc };
        long p0 = __builtin_bit_cast(long, f0);
        long p1 = __builtin_bit_cast(long, f1);

        // ---- PV (fp8): oa[ct] += V^T(c,kv) * P^T(kv,q) ----
        const u8* vb = Vbuf[cur];
        #pragma unroll
        for (int ct = 0; ct < 8; ct++) {
            const u8* vrow = vb + (size_t)(32 * ct + lq) * 32 + hi * 8;
            long v0 = *(const long*)(vrow + (vs1 << 4));
            long v1 = *(const long*)(vrow + ((vs1 ^ 1) << 4));
            oa[ct] = __builtin_amdgcn_mfma_f32_32x32x16_fp8_fp8(v0, p0, oa[ct], 0, 0, 0);
            oa[ct] = __builtin_amdgcn_mfma_f32_32x32x16_fp8_fp8(v1, p1, oa[ct], 0, 0, 0);
        }
        __syncthreads();   // one barrier/step (2 waves)
    }

    float lt = l_run + __shfl_xor(l_run, 32);
    float rinv = 1.f / lt;
    u16* Ob = O + (size_t)b * (HWPX * CH) + (size_t)(q0 + lq) * 256;
    #pragma unroll
    for (int ct = 0; ct < 8; ct++) {
        #pragma unroll
        for (int rg = 0; rg < 4; rg++) {
            u16* dst = Ob + 32 * ct + 8 * rg + 4 * hi;
            dst[0] = f2bf(oa[ct][rg * 4 + 0] * rinv);
            dst[1] = f2bf(oa[ct][rg * 4 + 1] * rinv);
            dst[2] = f2bf(oa[ct][rg * 4 + 2] * rinv);
            dst[3] = f2bf(oa[ct][rg * 4 + 3] * rinv);
        }
    }
}

// ---------------- host launch ----------------
extern "C" void kernel_launch(void* const* d_in, const int* in_sizes, int n_in,
                              void* d_out, int out_size, void* d_ws, size_t ws_size,
                              hipStream_t stream)
{
    const float* x   = (const float*)d_in[0];
    const float* Wq  = (const float*)d_in[1];
    const float* bq  = (const float*)d_in[2];
    const float* Wk  = (const float*)d_in[3];
    const float* bk  = (const float*)d_in[4];
    const float* Wv  = (const float*)d_in[5];
    const float* bv  = (const float*)d_in[6];
    const float* Wo  = (const float*)d_in[7];
    const float* bo  = (const float*)d_in[8];
    const float* gqs = (const float*)d_in[9];
    const float* gqb = (const float*)d_in[10];
    const float* gks = (const float*)d_in[11];
    const float* gkb = (const float*)d_in[12];
    const float* gvs = (const float*)d_in[13];
    const float* gvb = (const float*)d_in[14];

    const size_t NEL  = (size_t)NB * HWPX * CH;   // 8388608
    const size_t XHB  = NEL * 2;                  // bf16 Xh / O buffer
    const size_t F8B  = NEL;                      // fp8 buffers
    const size_t WTB  = 4 * 65536 * 2;
    const size_t BIASB = 4 * 256 * 4;
    size_t need = XHB + 3 * F8B + WTB + BIASB;
    if (ws_size < need) return;

    char* w = (char*)d_ws;
    u16*  Xh   = (u16*)(w);                       // [B][p][c] bf16; O after V proj
    u8*   Qf8  = (u8*)(w + XHB);
    u8*   Kf8  = (u8*)(w + XHB + F8B);
    u8*   Vf8  = (u8*)(w + XHB + 2 * F8B);
    u16*  Wt   = (u16*)(w + XHB + 3 * F8B);
    float* bias = (float*)(w + XHB + 3 * F8B + WTB);

    wprep<<<dim3(1024), dim3(256), 0, stream>>>(Wq, bq, gqs, gqb, Wk, bk, gks, gkb,
                                                Wv, bv, gvs, gvb, Wo, bo, Wt, bias);
    gn_kernel<<<dim3(1024), dim3(256), 0, stream>>>(x, Xh);

    // Q,K -> fp8 [p][d] (interleaved cols)
    gemm_nt<0><<<dim3(4, 512), dim3(256), 0, stream>>>(Xh, Wt,           bias,       Qf8, nullptr, nullptr);
    gemm_nt<0><<<dim3(4, 512), dim3(256), 0, stream>>>(Xh, Wt + 65536,   bias + 256, Kf8, nullptr, nullptr);
    // V -> fp8 [c][p]
    gemm_nt<1><<<dim3(512, 4), dim3(256), 0, stream>>>(Wt + 131072, Xh,  bias + 512, Vf8, nullptr, nullptr);
    // attention (writes bf16 O into Xh; Xh dead after V proj)
    attn<<<dim3(512), dim3(128), 0, stream>>>(Qf8, Kf8, Vf8, Xh);
    // out = x + Wo^T O + bo
    gemm_nt<2><<<dim3(512, 4), dim3(256), 0, stream>>>(Wt + 196608, Xh,  bias + 768, nullptr, (float*)d_out, x);
}

// Round 11
// 146.777 us; speedup vs baseline: 1.0776x; 1.0776x over previous
//
#include <hip/hip_runtime.h>
#include <stdint.h>

// B=32, C=256, H=W=32 (HW=1024), GROUPS=32, EPS=1e-5.
// K0 wprep : Wt[d][c] bf16 (gs/scale folded), bias folded. q-scale = log2e/16.
// K1 gn    : single-read groupnorm (x held in 32 regs/thread), Xh[b][p][c] bf16.
// K2 gemm<0>: Q,K proj -> FP8 e4m3 [p][d], cols interleaved (d = n0+lr*4+nt).
//    gemm<1>: V proj -> FP8 [c][p].
//    gemm<2>: final out = x + Wo^T O + bo (fp32).
//    All gemms: 1-deep B-fragment software pipeline (break ds_read->MFMA chain).
// K3 attn  : full-FP8 flash attn, mfma_f32_32x32x16_fp8_fp8, grid 256, 4 waves.
//            EXPLICIT K/V fragment preload into registers (kf[16], vf[16]) to
//            break the per-MFMA ds_read latency chain (r9 was ~120cyc x 32/step).

#define NB 32
#define CH 256
#define HWPX 1024

typedef __bf16 bf16x8 __attribute__((ext_vector_type(8)));
typedef float f32x4 __attribute__((ext_vector_type(4)));
typedef float f32x16 __attribute__((ext_vector_type(16)));
typedef unsigned short u16;
typedef unsigned char u8;
typedef unsigned int u32;
typedef u16 u16x8 __attribute__((ext_vector_type(8)));
typedef u32 u32x2 __attribute__((ext_vector_type(2)));

__device__ __forceinline__ u16 f2bf(float f) {
    __bf16 h = (__bf16)f;
    return __builtin_bit_cast(u16, h);
}
__device__ __forceinline__ bf16x8 ldb8(const u16* p) {
    return __builtin_bit_cast(bf16x8, *(const u16x8*)p);
}
__device__ __forceinline__ u32 pkfp8(float a, float b, float c, float d) {
    int w = __builtin_amdgcn_cvt_pk_fp8_f32(a, b, 0, false);
    w = __builtin_amdgcn_cvt_pk_fp8_f32(c, d, w, true);
    return (u32)w;
}
__device__ __forceinline__ void gld_lds16(const u8* g, u8* l) {
    __builtin_amdgcn_global_load_lds(
        (const __attribute__((address_space(1))) void*)g,
        (__attribute__((address_space(3))) void*)l, 16, 0, 0);
}

// ---------------- K0: weight prep ----------------
__global__ __launch_bounds__(256) void wprep(
    const float* __restrict__ Wq, const float* __restrict__ bq,
    const float* __restrict__ gqs, const float* __restrict__ gqb,
    const float* __restrict__ Wk, const float* __restrict__ bk,
    const float* __restrict__ gks, const float* __restrict__ gkb,
    const float* __restrict__ Wv, const float* __restrict__ bv,
    const float* __restrict__ gvs, const float* __restrict__ gvb,
    const float* __restrict__ Wo, const float* __restrict__ bo,
    u16* __restrict__ Wt, float* __restrict__ bias)
{
    int m = blockIdx.x >> 8;
    int d = blockIdx.x & 255;
    int c = threadIdx.x;
    const float *W, *bb, *gs, *gb; float scale;
    const float QSC = 0.09016844005556021f;   // log2(e)/16
    if (m == 0)      { W = Wq; bb = bq; gs = gqs; gb = gqb; scale = QSC; }
    else if (m == 1) { W = Wk; bb = bk; gs = gks; gb = gkb; scale = 1.f; }
    else if (m == 2) { W = Wv; bb = bv; gs = gvs; gb = gvb; scale = 1.f; }
    else             { W = Wo; bb = bo; gs = nullptr; gb = nullptr; scale = 1.f; }
    float w   = W[c * 256 + d];
    float gsc = gs ? gs[c] : 1.f;
    float gbc = gb ? gb[c] : 0.f;
    Wt[((size_t)m << 16) + d * 256 + c] = f2bf(w * gsc * scale);
    __shared__ float red[256];
    red[c] = gbc * w;
    __syncthreads();
    for (int s = 128; s > 0; s >>= 1) { if (c < s) red[c] += red[c + s]; __syncthreads(); }
    if (c == 0) bias[m * 256 + d] = (bb[d] + red[0]) * scale;
}

// ---------------- K1: groupnorm, single x read ----------------
__global__ __launch_bounds__(256) void gn_kernel(const float* __restrict__ x,
                                                 u16* __restrict__ Xh)
{
    int blk = blockIdx.x;
    int b = blk >> 5, g = blk & 31;
    const float* base = x + (size_t)(b * 256 + g * 8) * 1024;
    int t = threadIdx.x;
    float v[32];
    float s = 0.f, s2 = 0.f;
    #pragma unroll
    for (int j = 0; j < 8; j++) {
        #pragma unroll
        for (int pi = 0; pi < 4; pi++) {
            float val = base[j * 1024 + pi * 256 + t];
            v[j * 4 + pi] = val;
            s += val; s2 += val * val;
        }
    }
    __shared__ float rs[256], rq[256];
    rs[t] = s; rq[t] = s2;
    __syncthreads();
    for (int k = 128; k > 0; k >>= 1) {
        if (t < k) { rs[t] += rs[t + k]; rq[t] += rq[t + k]; }
        __syncthreads();
    }
    float mu  = rs[0] * (1.f / 8192.f);
    float var = rq[0] * (1.f / 8192.f) - mu * mu;
    float rv  = rsqrtf(var + 1e-5f);
    u16* outp = Xh + (size_t)b * (HWPX * CH) + g * 8;
    #pragma unroll
    for (int pi = 0; pi < 4; pi++) {
        int p = pi * 256 + t;
        u16x8 tv;
        #pragma unroll
        for (int j = 0; j < 8; j++) tv[j] = f2bf((v[j * 4 + pi] - mu) * rv);
        *(u16x8*)(outp + (size_t)p * 256) = tv;
    }
}

// ---------------- K2/K4: NT GEMM, shared B-tile in LDS, 1-deep B pipeline ----------------
// MODE0: fp8 out [m][256], col = n0 + lr*4 + nt (interleaved), dword stores.
// MODE1: fp8 out Vc[b][m][p], natural cols, byte stores.
// MODE2: fp32 out + residual.
template <int MODE>
__global__ __launch_bounds__(256) void gemm_nt(
    const u16* __restrict__ A, const u16* __restrict__ Bm,
    const float* __restrict__ bias,
    u8* __restrict__ C8, float* __restrict__ Cf,
    const float* __restrict__ xres)
{
    __shared__ __align__(16) u16 Bt[64 * 256];
    int tid = threadIdx.x;
    int lane = tid & 63, wave = tid >> 6;
    int m0 = blockIdx.y * 64 + wave * 16;
    int n0 = blockIdx.x * 64;

    #pragma unroll
    for (int i = 0; i < 8; i++) {
        int G = i * 256 + tid;
        int row = G >> 5, g = G & 31;
        const u16* src = Bm + (size_t)(n0 + row) * 256 + ((g ^ (row & 7)) << 3);
        gld_lds16((const u8*)src, (u8*)(Bt + (size_t)(i * 256 + wave * 64) * 8));
    }

    int lr = lane & 15, hk = lane >> 4, lk = hk * 8;
    const u16* Ap = A + (size_t)(m0 + lr) * 256 + lk;
    bf16x8 af[8];
    #pragma unroll
    for (int kk = 0; kk < 8; kk++) af[kk] = ldb8(Ap + kk * 32);

    int rowm[4];
    #pragma unroll
    for (int nt = 0; nt < 4; nt++)
        rowm[nt] = (MODE == 0) ? (lr * 4 + nt) : (nt * 16 + lr);

    __syncthreads();

    f32x4 acc[4] = {};
    bf16x8 b0[4], b1[4];
    #pragma unroll
    for (int nt = 0; nt < 4; nt++) {
        int g = (0 * 4 + hk) ^ (rowm[nt] & 7);
        b0[nt] = ldb8(Bt + (size_t)(rowm[nt] * 32 + g) * 8);
    }
    #pragma unroll
    for (int kk = 0; kk < 8; kk++) {
        if (kk & 1) {
            if (kk < 7) {
                #pragma unroll
                for (int nt = 0; nt < 4; nt++) {
                    int g = ((kk + 1) * 4 + hk) ^ (rowm[nt] & 7);
                    b0[nt] = ldb8(Bt + (size_t)(rowm[nt] * 32 + g) * 8);
                }
            }
            #pragma unroll
            for (int nt = 0; nt < 4; nt++)
                acc[nt] = __builtin_amdgcn_mfma_f32_16x16x32_bf16(af[kk], b1[nt], acc[nt], 0, 0, 0);
        } else {
            #pragma unroll
            for (int nt = 0; nt < 4; nt++) {
                int g = ((kk + 1) * 4 + hk) ^ (rowm[nt] & 7);
                b1[nt] = ldb8(Bt + (size_t)(rowm[nt] * 32 + g) * 8);
            }
            #pragma unroll
            for (int nt = 0; nt < 4; nt++)
                acc[nt] = __builtin_amdgcn_mfma_f32_16x16x32_bf16(af[kk], b0[nt], acc[nt], 0, 0, 0);
        }
    }
    int rbase = m0 + (hk << 2);
    if (MODE == 0) {
        int colbase = n0 + lr * 4;
        #pragma unroll
        for (int j = 0; j < 4; j++) {
            int row = rbase + j;
            u32 w = pkfp8(acc[0][j] + bias[colbase],
                          acc[1][j] + bias[colbase + 1],
                          acc[2][j] + bias[colbase + 2],
                          acc[3][j] + bias[colbase + 3]);
            *(u32*)(C8 + (size_t)row * 256 + colbase) = w;
        }
    } else {
        #pragma unroll
        for (int nt = 0; nt < 4; nt++) {
            int col = n0 + nt * 16 + lr;
            int b = col >> 10, p = col & 1023;
            #pragma unroll
            for (int j = 0; j < 4; j++) {
                int row = rbase + j;
                float v = acc[nt][j] + bias[row];
                size_t off = (size_t)b * (CH * HWPX) + (size_t)row * 1024 + p;
                if (MODE == 1) {
                    int w = __builtin_amdgcn_cvt_pk_fp8_f32(v, v, 0, false);
                    C8[off] = (u8)(w & 0xff);
                } else {
                    Cf[off] = v + xres[off];
                }
            }
        }
    }
}

// ---------------- K3: full-FP8 flash attention, explicit K/V reg preload ----------------
// grid 256 (1 block/CU), 4 waves x 32 q-rows, KV step 32, 32 steps.
// S^T = mfma(K, Q); lane owns q = q0+(lane&31); P packed to fp8 in-register.
__global__ __launch_bounds__(256, 1) void attn(
    const u8* __restrict__ Qf8, const u8* __restrict__ Kf8,
    const u8* __restrict__ Vf8, u16* __restrict__ O)
{
    __shared__ __align__(16) u8 Kbuf[2][32 * 256];   // 2 x 8 KB, granule(16B) ^= row&7
    __shared__ __align__(16) u8 Vbuf[2][256 * 32];   // 2 x 8 KB, granule ^= (c>>2)&1

    int tid = threadIdx.x;
    int lane = tid & 63, wave = tid >> 6;
    int bid = blockIdx.x;
    int b  = (bid & 7) * 4 + (bid >> 6);   // XCD x hosts batches 4x..4x+3
    int qb = (bid >> 3) & 7;
    int q0 = qb * 128 + wave * 32;

    const u8* Qb = Qf8 + (size_t)b * (HWPX * CH);
    const u8* Kb = Kf8 + (size_t)b * (HWPX * CH);
    const u8* Vb = Vf8 + (size_t)b * (CH * HWPX);

    int lq = lane & 31, hi = lane >> 5;
    int kswz = lq & 7;
    int vs1  = (lq >> 2) & 1;

    // staging source offsets (inverse-swizzled, LDS dest linear)
    int koff[2], voff[2];
    #pragma unroll
    for (int i = 0; i < 2; i++) {
        int G = i * 256 + tid;
        int kr = G >> 4, kg = G & 15;
        koff[i] = kr * 256 + ((kg ^ (kr & 7)) << 4);
        int vr = G >> 1, vg = G & 1;
        voff[i] = vr * 1024 + ((vg ^ ((vr >> 2) & 1)) << 4);
    }

    // Q fragments: qf[f] = Q[q0+lq][f*16 + hi*8 .. +7] (fp8, 8 bytes)
    long qf[16];
    #pragma unroll
    for (int f = 0; f < 16; f++)
        qf[f] = *(const long*)(Qb + (size_t)(q0 + lq) * 256 + f * 16 + hi * 8);

    f32x16 oa[8] = {};
    float m_run = -1e30f, l_run = 0.f;

    // prologue: stage tile 0
    #pragma unroll
    for (int i = 0; i < 2; i++)
        gld_lds16(Kb + koff[i], &Kbuf[0][0] + (size_t)(i * 256 + wave * 64) * 16);
    #pragma unroll
    for (int i = 0; i < 2; i++)
        gld_lds16(Vb + voff[i], &Vbuf[0][0] + (size_t)(i * 256 + wave * 64) * 16);
    __syncthreads();

    for (int t = 0; t < 32; ++t) {
        int cur = t & 1;
        if (t < 31) {
            const u8* ks = Kb + (size_t)(t + 1) * (32 * 256);
            const u8* vs = Vb + (t + 1) * 32;
            #pragma unroll
            for (int i = 0; i < 2; i++)
                gld_lds16(ks + koff[i], &Kbuf[cur ^ 1][0] + (size_t)(i * 256 + wave * 64) * 16);
            #pragma unroll
            for (int i = 0; i < 2; i++)
                gld_lds16(vs + voff[i], &Vbuf[cur ^ 1][0] + (size_t)(i * 256 + wave * 64) * 16);
        }

        // ---- QK^T (fp8): PRELOAD all 16 K-fragments, then MFMA burst ----
        const u8* kb = Kbuf[cur];
        f32x16 s0 = {}, s1 = {};
        {
            long kf[16];
            #pragma unroll
            for (int j = 0; j < 16; j++)
                kf[j] = *(const long*)(kb + (size_t)lq * 256 + ((j ^ kswz) << 4) + hi * 8);
            #pragma unroll
            for (int ff = 0; ff < 8; ff++) {
                s0 = __builtin_amdgcn_mfma_f32_32x32x16_fp8_fp8(kf[2 * ff],     qf[2 * ff],     s0, 0, 0, 0);
                s1 = __builtin_amdgcn_mfma_f32_32x32x16_fp8_fp8(kf[2 * ff + 1], qf[2 * ff + 1], s1, 0, 0, 0);
            }
        }

        // ---- PRELOAD all 16 V-fragments (latency hides under softmax VALU) ----
        long vf[16];
        {
            const u8* vb = Vbuf[cur];
            #pragma unroll
            for (int ct = 0; ct < 8; ct++) {
                const u8* vrow = vb + (size_t)(32 * ct + lq) * 32 + hi * 8;
                vf[2 * ct]     = *(const long*)(vrow + (vs1 << 4));
                vf[2 * ct + 1] = *(const long*)(vrow + ((vs1 ^ 1) << 4));
            }
        }

        float s[16];
        #pragma unroll
        for (int r = 0; r < 16; r++) s[r] = s0[r] + s1[r];

        // ---- lane-local defer-max softmax (log2 domain) ----
        float m01 = fmaxf(s[0], s[1]),   m23 = fmaxf(s[2], s[3]);
        float m45 = fmaxf(s[4], s[5]),   m67 = fmaxf(s[6], s[7]);
        float m89 = fmaxf(s[8], s[9]),   mab = fmaxf(s[10], s[11]);
        float mcd = fmaxf(s[12], s[13]), mef = fmaxf(s[14], s[15]);
        float mloc = fmaxf(fmaxf(fmaxf(m01, m23), fmaxf(m45, m67)),
                           fmaxf(fmaxf(m89, mab), fmaxf(mcd, mef)));
        if (!__all(mloc - m_run <= 4.f)) {          // rare: t==0 or max jumped
            float mo = fmaxf(mloc, __shfl_xor(mloc, 32));
            float mn = fmaxf(m_run, mo);
            float sc = exp2f(m_run - mn);
            m_run = mn;
            l_run *= sc;
            #pragma unroll
            for (int ct = 0; ct < 8; ct++) {
                #pragma unroll
                for (int r = 0; r < 16; r++) oa[ct][r] *= sc;
            }
        }
        float p[16];
        #pragma unroll
        for (int r = 0; r < 16; r++) p[r] = exp2f(s[r] - m_run);   // <= 2^4
        l_run += (((p[0]+p[1])+(p[2]+p[3]))+((p[4]+p[5])+(p[6]+p[7])))
               + (((p[8]+p[9])+(p[10]+p[11]))+((p[12]+p[13])+(p[14]+p[15])));

        // ---- pack P^T to fp8 B-fragments in-register ----
        u32 a  = pkfp8(p[0],  p[1],  p[2],  p[3]);
        u32 bb = pkfp8(p[4],  p[5],  p[6],  p[7]);
        u32 c  = pkfp8(p[8],  p[9],  p[10], p[11]);
        u32 d  = pkfp8(p[12], p[13], p[14], p[15]);
        u32 xa = (u32)__shfl_xor((int)a, 32),  xb = (u32)__shfl_xor((int)bb, 32);
        u32 xc = (u32)__shfl_xor((int)c, 32),  xd = (u32)__shfl_xor((int)d, 32);
        u32x2 f0 = { hi ? xb : a, hi ? bb : xa };
        u32x2 f1 = { hi ? xd : c, hi ? d  : xc };
        long p0 = __builtin_bit_cast(long, f0);
        long p1 = __builtin_bit_cast(long, f1);

        // ---- PV (fp8) from preloaded registers ----
        #pragma unroll
        for (int ct = 0; ct < 8; ct++) {
            oa[ct] = __builtin_amdgcn_mfma_f32_32x32x16_fp8_fp8(vf[2 * ct],     p0, oa[ct], 0, 0, 0);
            oa[ct] = __builtin_amdgcn_mfma_f32_32x32x16_fp8_fp8(vf[2 * ct + 1], p1, oa[ct], 0, 0, 0);
        }
        __syncthreads();   // one barrier/step
    }

    float lt = l_run + __shfl_xor(l_run, 32);
    float rinv = 1.f / lt;
    u16* Ob = O + (size_t)b * (HWPX * CH) + (size_t)(q0 + lq) * 256;
    #pragma unroll
    for (int ct = 0; ct < 8; ct++) {
        #pragma unroll
        for (int rg = 0; rg < 4; rg++) {
            u16* dst = Ob + 32 * ct + 8 * rg + 4 * hi;
            dst[0] = f2bf(oa[ct][rg * 4 + 0] * rinv);
            dst[1] = f2bf(oa[ct][rg * 4 + 1] * rinv);
            dst[2] = f2bf(oa[ct][rg * 4 + 2] * rinv);
            dst[3] = f2bf(oa[ct][rg * 4 + 3] * rinv);
        }
    }
}

// ---------------- host launch ----------------
extern "C" void kernel_launch(void* const* d_in, const int* in_sizes, int n_in,
                              void* d_out, int out_size, void* d_ws, size_t ws_size,
                              hipStream_t stream)
{
    const float* x   = (const float*)d_in[0];
    const float* Wq  = (const float*)d_in[1];
    const float* bq  = (const float*)d_in[2];
    const float* Wk  = (const float*)d_in[3];
    const float* bk  = (const float*)d_in[4];
    const float* Wv  = (const float*)d_in[5];
    const float* bv  = (const float*)d_in[6];
    const float* Wo  = (const float*)d_in[7];
    const float* bo  = (const float*)d_in[8];
    const float* gqs = (const float*)d_in[9];
    const float* gqb = (const float*)d_in[10];
    const float* gks = (const float*)d_in[11];
    const float* gkb = (const float*)d_in[12];
    const float* gvs = (const float*)d_in[13];
    const float* gvb = (const float*)d_in[14];

    const size_t NEL  = (size_t)NB * HWPX * CH;   // 8388608
    const size_t XHB  = NEL * 2;                  // bf16 Xh / O buffer
    const size_t F8B  = NEL;                      // fp8 buffers
    const size_t WTB  = 4 * 65536 * 2;
    const size_t BIASB = 4 * 256 * 4;
    size_t need = XHB + 3 * F8B + WTB + BIASB;
    if (ws_size < need) return;

    char* w = (char*)d_ws;
    u16*  Xh   = (u16*)(w);                       // [B][p][c] bf16; O after V proj
    u8*   Qf8  = (u8*)(w + XHB);
    u8*   Kf8  = (u8*)(w + XHB + F8B);
    u8*   Vf8  = (u8*)(w + XHB + 2 * F8B);
    u16*  Wt   = (u16*)(w + XHB + 3 * F8B);
    float* bias = (float*)(w + XHB + 3 * F8B + WTB);

    wprep<<<dim3(1024), dim3(256), 0, stream>>>(Wq, bq, gqs, gqb, Wk, bk, gks, gkb,
                                                Wv, bv, gvs, gvb, Wo, bo, Wt, bias);
    gn_kernel<<<dim3(1024), dim3(256), 0, stream>>>(x, Xh);

    // Q,K -> fp8 [p][d] (interleaved cols)
    gemm_nt<0><<<dim3(4, 512), dim3(256), 0, stream>>>(Xh, Wt,           bias,       Qf8, nullptr, nullptr);
    gemm_nt<0><<<dim3(4, 512), dim3(256), 0, stream>>>(Xh, Wt + 65536,   bias + 256, Kf8, nullptr, nullptr);
    // V -> fp8 [c][p]
    gemm_nt<1><<<dim3(512, 4), dim3(256), 0, stream>>>(Wt + 131072, Xh,  bias + 512, Vf8, nullptr, nullptr);
    // attention (writes bf16 O into Xh; Xh dead after V proj)
    attn<<<dim3(256), dim3(256), 0, stream>>>(Qf8, Kf8, Vf8, Xh);
    // out = x + Wo^T O + bo
    gemm_nt<2><<<dim3(512, 4), dim3(256), 0, stream>>>(Wt + 196608, Xh,  bias + 768, nullptr, (float*)d_out, x);
}

// Round 12
// 132.432 us; speedup vs baseline: 1.1943x; 1.1083x over previous
//
#include <hip/hip_runtime.h>
#include <stdint.h>

// B=32, C=256, H=W=32 (HW=1024), GROUPS=32, EPS=1e-5.
// K0 wprep : Wt[d][c] bf16 (gs/scale folded), bias folded. q-scale = log2e/16.
// K1 gn    : single-read groupnorm, Xh[b][p][c] bf16.
// K2 gemm<0>: Q -> FP8 [p][d], d interleaved (d = n0+lr*4+nt), dword stores.
//    gemm<3>: K -> FP8 kv-blocked: [b][T=p>>5][j=d>>4][p&31][d&15]  (8KB tiles)
//    gemm<1>: V -> FP8 kv-blocked: [b][T=p>>5][c][p&31]             (8KB tiles)
//    gemm<2>: final out = x + Wo^T O + bo (fp32).
// K3 attn  : FP8 flash attn, 512-thr blocks (4 q-waves x 2 kv-halves), grid 256.
//            2 waves/SIMD, kv-split merged IN-LDS at end. All LDS K/V reads are
//            lane-linear 512B (zero bank conflicts); staging 1KB-contiguous.

#define NB 32
#define CH 256
#define HWPX 1024

typedef __bf16 bf16x8 __attribute__((ext_vector_type(8)));
typedef float f32x4 __attribute__((ext_vector_type(4)));
typedef float f32x16 __attribute__((ext_vector_type(16)));
typedef unsigned short u16;
typedef unsigned char u8;
typedef unsigned int u32;
typedef u16 u16x8 __attribute__((ext_vector_type(8)));
typedef u32 u32x2 __attribute__((ext_vector_type(2)));

__device__ __forceinline__ u16 f2bf(float f) {
    __bf16 h = (__bf16)f;
    return __builtin_bit_cast(u16, h);
}
__device__ __forceinline__ bf16x8 ldb8(const u16* p) {
    return __builtin_bit_cast(bf16x8, *(const u16x8*)p);
}
__device__ __forceinline__ u32 pkfp8(float a, float b, float c, float d) {
    int w = __builtin_amdgcn_cvt_pk_fp8_f32(a, b, 0, false);
    w = __builtin_amdgcn_cvt_pk_fp8_f32(c, d, w, true);
    return (u32)w;
}
__device__ __forceinline__ void gld_lds16(const u8* g, u8* l) {
    __builtin_amdgcn_global_load_lds(
        (const __attribute__((address_space(1))) void*)g,
        (__attribute__((address_space(3))) void*)l, 16, 0, 0);
}

// ---------------- K0: weight prep ----------------
__global__ __launch_bounds__(256) void wprep(
    const float* __restrict__ Wq, const float* __restrict__ bq,
    const float* __restrict__ gqs, const float* __restrict__ gqb,
    const float* __restrict__ Wk, const float* __restrict__ bk,
    const float* __restrict__ gks, const float* __restrict__ gkb,
    const float* __restrict__ Wv, const float* __restrict__ bv,
    const float* __restrict__ gvs, const float* __restrict__ gvb,
    const float* __restrict__ Wo, const float* __restrict__ bo,
    u16* __restrict__ Wt, float* __restrict__ bias)
{
    int m = blockIdx.x >> 8;
    int d = blockIdx.x & 255;
    int c = threadIdx.x;
    const float *W, *bb, *gs, *gb; float scale;
    const float QSC = 0.09016844005556021f;   // log2(e)/16
    if (m == 0)      { W = Wq; bb = bq; gs = gqs; gb = gqb; scale = QSC; }
    else if (m == 1) { W = Wk; bb = bk; gs = gks; gb = gkb; scale = 1.f; }
    else if (m == 2) { W = Wv; bb = bv; gs = gvs; gb = gvb; scale = 1.f; }
    else             { W = Wo; bb = bo; gs = nullptr; gb = nullptr; scale = 1.f; }
    float w   = W[c * 256 + d];
    float gsc = gs ? gs[c] : 1.f;
    float gbc = gb ? gb[c] : 0.f;
    Wt[((size_t)m << 16) + d * 256 + c] = f2bf(w * gsc * scale);
    __shared__ float red[256];
    red[c] = gbc * w;
    __syncthreads();
    for (int s = 128; s > 0; s >>= 1) { if (c < s) red[c] += red[c + s]; __syncthreads(); }
    if (c == 0) bias[m * 256 + d] = (bb[d] + red[0]) * scale;
}

// ---------------- K1: groupnorm, single x read ----------------
__global__ __launch_bounds__(256) void gn_kernel(const float* __restrict__ x,
                                                 u16* __restrict__ Xh)
{
    int blk = blockIdx.x;
    int b = blk >> 5, g = blk & 31;
    const float* base = x + (size_t)(b * 256 + g * 8) * 1024;
    int t = threadIdx.x;
    float v[32];
    float s = 0.f, s2 = 0.f;
    #pragma unroll
    for (int j = 0; j < 8; j++) {
        #pragma unroll
        for (int pi = 0; pi < 4; pi++) {
            float val = base[j * 1024 + pi * 256 + t];
            v[j * 4 + pi] = val;
            s += val; s2 += val * val;
        }
    }
    __shared__ float rs[256], rq[256];
    rs[t] = s; rq[t] = s2;
    __syncthreads();
    for (int k = 128; k > 0; k >>= 1) {
        if (t < k) { rs[t] += rs[t + k]; rq[t] += rq[t + k]; }
        __syncthreads();
    }
    float mu  = rs[0] * (1.f / 8192.f);
    float var = rq[0] * (1.f / 8192.f) - mu * mu;
    float rv  = rsqrtf(var + 1e-5f);
    u16* outp = Xh + (size_t)b * (HWPX * CH) + g * 8;
    #pragma unroll
    for (int pi = 0; pi < 4; pi++) {
        int p = pi * 256 + t;
        u16x8 tv;
        #pragma unroll
        for (int j = 0; j < 8; j++) tv[j] = f2bf((v[j * 4 + pi] - mu) * rv);
        *(u16x8*)(outp + (size_t)p * 256) = tv;
    }
}

// ---------------- K2/K4: NT GEMM, shared B-tile in LDS, 1-deep B pipeline ----------------
// MODE0: Q fp8 [m][256], col = n0 + lr*4 + nt (interleaved), dword stores.
// MODE3: K fp8 kv-blocked, same interleave, dword stores.
// MODE1: V fp8 kv-blocked [b][p>>5][c][p&31], byte stores.
// MODE2: fp32 out + residual.
template <int MODE>
__global__ __launch_bounds__(256) void gemm_nt(
    const u16* __restrict__ A, const u16* __restrict__ Bm,
    const float* __restrict__ bias,
    u8* __restrict__ C8, float* __restrict__ Cf,
    const float* __restrict__ xres)
{
    __shared__ __align__(16) u16 Bt[64 * 256];
    int tid = threadIdx.x;
    int lane = tid & 63, wave = tid >> 6;
    int m0 = blockIdx.y * 64 + wave * 16;
    int n0 = blockIdx.x * 64;

    #pragma unroll
    for (int i = 0; i < 8; i++) {
        int G = i * 256 + tid;
        int row = G >> 5, g = G & 31;
        const u16* src = Bm + (size_t)(n0 + row) * 256 + ((g ^ (row & 7)) << 3);
        gld_lds16((const u8*)src, (u8*)(Bt + (size_t)(i * 256 + wave * 64) * 8));
    }

    int lr = lane & 15, hk = lane >> 4, lk = hk * 8;
    const u16* Ap = A + (size_t)(m0 + lr) * 256 + lk;
    bf16x8 af[8];
    #pragma unroll
    for (int kk = 0; kk < 8; kk++) af[kk] = ldb8(Ap + kk * 32);

    int rowm[4];
    #pragma unroll
    for (int nt = 0; nt < 4; nt++)
        rowm[nt] = (MODE == 0 || MODE == 3) ? (lr * 4 + nt) : (nt * 16 + lr);

    __syncthreads();

    f32x4 acc[4] = {};
    bf16x8 b0[4], b1[4];
    #pragma unroll
    for (int nt = 0; nt < 4; nt++) {
        int g = (0 * 4 + hk) ^ (rowm[nt] & 7);
        b0[nt] = ldb8(Bt + (size_t)(rowm[nt] * 32 + g) * 8);
    }
    #pragma unroll
    for (int kk = 0; kk < 8; kk++) {
        if (kk & 1) {
            if (kk < 7) {
                #pragma unroll
                for (int nt = 0; nt < 4; nt++) {
                    int g = ((kk + 1) * 4 + hk) ^ (rowm[nt] & 7);
                    b0[nt] = ldb8(Bt + (size_t)(rowm[nt] * 32 + g) * 8);
                }
            }
            #pragma unroll
            for (int nt = 0; nt < 4; nt++)
                acc[nt] = __builtin_amdgcn_mfma_f32_16x16x32_bf16(af[kk], b1[nt], acc[nt], 0, 0, 0);
        } else {
            #pragma unroll
            for (int nt = 0; nt < 4; nt++) {
                int g = ((kk + 1) * 4 + hk) ^ (rowm[nt] & 7);
                b1[nt] = ldb8(Bt + (size_t)(rowm[nt] * 32 + g) * 8);
            }
            #pragma unroll
            for (int nt = 0; nt < 4; nt++)
                acc[nt] = __builtin_amdgcn_mfma_f32_16x16x32_bf16(af[kk], b0[nt], acc[nt], 0, 0, 0);
        }
    }
    int rbase = m0 + (hk << 2);
    if (MODE == 0 || MODE == 3) {
        int colbase = n0 + lr * 4;
        #pragma unroll
        for (int j = 0; j < 4; j++) {
            int row = rbase + j;
            u32 w = pkfp8(acc[0][j] + bias[colbase],
                          acc[1][j] + bias[colbase + 1],
                          acc[2][j] + bias[colbase + 2],
                          acc[3][j] + bias[colbase + 3]);
            size_t off;
            if (MODE == 0) {
                off = (size_t)row * 256 + colbase;
            } else {
                // kv-blocked K: [b][p>>5][d>>4][p&31][d&15]
                off = (size_t)(row >> 10) * 262144 + (size_t)((row & 1023) >> 5) * 8192
                    + (size_t)(colbase >> 4) * 512 + (row & 31) * 16 + (colbase & 15);
            }
            *(u32*)(C8 + off) = w;
        }
    } else {
        #pragma unroll
        for (int nt = 0; nt < 4; nt++) {
            int col = n0 + nt * 16 + lr;
            int b = col >> 10, p = col & 1023;
            #pragma unroll
            for (int j = 0; j < 4; j++) {
                int row = rbase + j;
                float v = acc[nt][j] + bias[row];
                if (MODE == 1) {
                    // kv-blocked V: [b][p>>5][c][p&31]
                    size_t off = (size_t)b * 262144 + (size_t)(p >> 5) * 8192
                               + (size_t)row * 32 + (p & 31);
                    int w = __builtin_amdgcn_cvt_pk_fp8_f32(v, v, 0, false);
                    C8[off] = (u8)(w & 0xff);
                } else {
                    size_t off = (size_t)b * (CH * HWPX) + (size_t)row * 1024 + p;
                    Cf[off] = v + xres[off];
                }
            }
        }
    }
}

// ---------------- K3: FP8 flash attention, in-block kv-split ----------------
// grid 256, 512 thr (8 waves = 4 q-tiles x 2 kv-halves), 2 waves/SIMD.
// S^T = mfma(K, Q); lane owns q = q0+(lane&31); P packed to fp8 in-register.
// LDS: K 2halves x dbuf x 8KB + V same = 64KB + 2KB ml. Merge in-LDS at end.
__global__ __launch_bounds__(512, 2) void attn(
    const u8* __restrict__ Qf8, const u8* __restrict__ Kf8,
    const u8* __restrict__ Vf8, u16* __restrict__ O)
{
    __shared__ __align__(16) u8 SM[67584];

    int tid = threadIdx.x;
    int lane = tid & 63, wave = tid >> 6;
    int wq = wave & 3, h = wave >> 2;
    int bid = blockIdx.x;
    int b  = (bid & 7) * 4 + (bid >> 6);   // XCD x hosts batches 4x..4x+3
    int qb = (bid >> 3) & 7;
    int q0 = qb * 128 + wq * 32;
    int lq = lane & 31, hi = lane >> 5;

    const u8* Qb = Qf8 + (size_t)b * 262144;
    const u8* Kb = Kf8 + (size_t)b * 262144 + (size_t)h * 131072;  // 16 tiles x 8KB
    const u8* Vb = Vf8 + (size_t)b * 262144 + (size_t)h * 131072;

    u8* Kl0 = SM + (size_t)(h * 2) * 8192;
    u8* Kl1 = SM + (size_t)(h * 2 + 1) * 8192;
    u8* Vl0 = SM + 32768 + (size_t)(h * 2) * 8192;
    u8* Vl1 = SM + 32768 + (size_t)(h * 2 + 1) * 8192;
    float* ml = (float*)(SM + 65536);

    // Q fragments: qf[f] = Q[q0+lq][f*16 + hi*8 .. +7]
    long qf[16];
    #pragma unroll
    for (int f = 0; f < 16; f++)
        qf[f] = *(const long*)(Qb + (size_t)(q0 + lq) * 256 + f * 16 + hi * 8);

    f32x16 oa[8] = {};
    float m_run = -1e30f, l_run = 0.f;

    // prologue: stage tile 0 of this half (contiguous 1KB per instr)
    #pragma unroll
    for (int i = 0; i < 2; i++) {
        int Gs = (i * 256 + wq * 64 + lane) << 4;
        int Gd = (i * 256 + wq * 64) << 4;
        gld_lds16(Kb + Gs, Kl0 + Gd);
        gld_lds16(Vb + Gs, Vl0 + Gd);
    }
    __syncthreads();

    for (int t = 0; t < 16; ++t) {
        u8* kcur = (t & 1) ? Kl1 : Kl0;
        u8* vcur = (t & 1) ? Vl1 : Vl0;
        if (t < 15) {
            u8* knxt = (t & 1) ? Kl0 : Kl1;
            u8* vnxt = (t & 1) ? Vl0 : Vl1;
            const u8* ks = Kb + (size_t)(t + 1) * 8192;
            const u8* vs = Vb + (size_t)(t + 1) * 8192;
            #pragma unroll
            for (int i = 0; i < 2; i++) {
                int Gs = (i * 256 + wq * 64 + lane) << 4;
                int Gd = (i * 256 + wq * 64) << 4;
                gld_lds16(ks + Gs, knxt + Gd);
                gld_lds16(vs + Gs, vnxt + Gd);
            }
        }

        // ---- QK^T: lane-linear LDS reads (j*512 + lq*16 + hi*8) ----
        f32x16 s0 = {}, s1 = {};
        #pragma unroll
        for (int ff = 0; ff < 8; ff++) {
            long k0 = *(const long*)(kcur + (2 * ff) * 512 + lq * 16 + hi * 8);
            s0 = __builtin_amdgcn_mfma_f32_32x32x16_fp8_fp8(k0, qf[2 * ff], s0, 0, 0, 0);
            long k1 = *(const long*)(kcur + (2 * ff + 1) * 512 + lq * 16 + hi * 8);
            s1 = __builtin_amdgcn_mfma_f32_32x32x16_fp8_fp8(k1, qf[2 * ff + 1], s1, 0, 0, 0);
        }

        // ---- V preload (lane-linear), latency hides under softmax ----
        long vf[16];
        #pragma unroll
        for (int ct = 0; ct < 8; ct++) {
            vf[2 * ct]     = *(const long*)(vcur + ct * 1024 + lq * 16 + hi * 8);
            vf[2 * ct + 1] = *(const long*)(vcur + ct * 1024 + 512 + lq * 16 + hi * 8);
        }

        float s[16];
        #pragma unroll
        for (int r = 0; r < 16; r++) s[r] = s0[r] + s1[r];

        // ---- lane-local defer-max softmax (log2 domain) ----
        float m01 = fmaxf(s[0], s[1]),   m23 = fmaxf(s[2], s[3]);
        float m45 = fmaxf(s[4], s[5]),   m67 = fmaxf(s[6], s[7]);
        float m89 = fmaxf(s[8], s[9]),   mab = fmaxf(s[10], s[11]);
        float mcd = fmaxf(s[12], s[13]), mef = fmaxf(s[14], s[15]);
        float mloc = fmaxf(fmaxf(fmaxf(m01, m23), fmaxf(m45, m67)),
                           fmaxf(fmaxf(m89, mab), fmaxf(mcd, mef)));
        if (!__all(mloc - m_run <= 4.f)) {          // rare: t==0 or max jumped
            float mo = fmaxf(mloc, __shfl_xor(mloc, 32));
            float mn = fmaxf(m_run, mo);
            float sc = exp2f(m_run - mn);
            m_run = mn;
            l_run *= sc;
            #pragma unroll
            for (int ct = 0; ct < 8; ct++) {
                #pragma unroll
                for (int r = 0; r < 16; r++) oa[ct][r] *= sc;
            }
        }
        float p[16];
        #pragma unroll
        for (int r = 0; r < 16; r++) p[r] = exp2f(s[r] - m_run);   // <= 2^4
        l_run += (((p[0]+p[1])+(p[2]+p[3]))+((p[4]+p[5])+(p[6]+p[7])))
               + (((p[8]+p[9])+(p[10]+p[11]))+((p[12]+p[13])+(p[14]+p[15])));

        // ---- pack P^T to fp8 B-fragments in-register ----
        u32 a  = pkfp8(p[0],  p[1],  p[2],  p[3]);
        u32 bb = pkfp8(p[4],  p[5],  p[6],  p[7]);
        u32 c  = pkfp8(p[8],  p[9],  p[10], p[11]);
        u32 d  = pkfp8(p[12], p[13], p[14], p[15]);
        u32 xa = (u32)__shfl_xor((int)a, 32),  xb = (u32)__shfl_xor((int)bb, 32);
        u32 xc = (u32)__shfl_xor((int)c, 32),  xd = (u32)__shfl_xor((int)d, 32);
        u32x2 f0 = { hi ? xb : a, hi ? bb : xa };
        u32x2 f1 = { hi ? xd : c, hi ? d  : xc };
        long p0 = __builtin_bit_cast(long, f0);
        long p1 = __builtin_bit_cast(long, f1);

        // ---- PV (fp8) from preloaded registers ----
        #pragma unroll
        for (int ct = 0; ct < 8; ct++) {
            oa[ct] = __builtin_amdgcn_mfma_f32_32x32x16_fp8_fp8(vf[2 * ct],     p0, oa[ct], 0, 0, 0);
            oa[ct] = __builtin_amdgcn_mfma_f32_32x32x16_fp8_fp8(vf[2 * ct + 1], p1, oa[ct], 0, 0, 0);
        }
        __syncthreads();   // one barrier/step; syncs both halves
    }

    // ---- in-LDS merge of the two kv-halves ----
    float lt = l_run + __shfl_xor(l_run, 32);
    if (hi == 0) {
        ml[(wave * 32 + lq) * 2]     = m_run;
        ml[(wave * 32 + lq) * 2 + 1] = lt;
    }
    __syncthreads();
    int pw = wave ^ 4;   // partner wave (other half, same q-tile)
    float m_o = ml[(pw * 32 + lq) * 2];
    float l_o = ml[(pw * 32 + lq) * 2 + 1];
    float mm  = fmaxf(m_run, m_o);
    float denom = exp2f(m_run - mm) * lt + exp2f(m_o - mm) * l_o;
    float myw = exp2f(m_run - mm) / denom;
    #pragma unroll
    for (int ct = 0; ct < 8; ct++) {
        #pragma unroll
        for (int r = 0; r < 16; r++) oa[ct][r] *= myw;
    }

    float* mbuf = (float*)SM;   // 64KB chunk buffer (K/V space, loop is done)
    u16* Ob = O + (size_t)b * (HWPX * CH) + (size_t)(q0 + lq) * 256;
    for (int ch = 0; ch < 2; ++ch) {
        if (h == 1) {
            #pragma unroll
            for (int ctl = 0; ctl < 4; ++ctl) {
                int ct = ch * 4 + ctl;
                #pragma unroll
                for (int r = 0; r < 16; ++r) {
                    int crow = (r & 3) + 8 * (r >> 2) + 4 * hi;
                    mbuf[((wq * 4 + ctl) * 32 + crow) * 32 + lq] = oa[ct][r];
                }
            }
        }
        __syncthreads();
        if (h == 0) {
            #pragma unroll
            for (int ctl = 0; ctl < 4; ++ctl) {
                int ct = ch * 4 + ctl;
                #pragma unroll
                for (int rg = 0; rg < 4; ++rg) {
                    u16* dst = Ob + 32 * ct + 8 * rg + 4 * hi;
                    #pragma unroll
                    for (int v = 0; v < 4; ++v) {
                        int r = rg * 4 + v;
                        int crow = v + 8 * rg + 4 * hi;
                        float sum = oa[ct][r] + mbuf[((wq * 4 + ctl) * 32 + crow) * 32 + lq];
                        dst[v] = f2bf(sum);
                    }
                }
            }
        }
        __syncthreads();
    }
}

// ---------------- host launch ----------------
extern "C" void kernel_launch(void* const* d_in, const int* in_sizes, int n_in,
                              void* d_out, int out_size, void* d_ws, size_t ws_size,
                              hipStream_t stream)
{
    const float* x   = (const float*)d_in[0];
    const float* Wq  = (const float*)d_in[1];
    const float* bq  = (const float*)d_in[2];
    const float* Wk  = (const float*)d_in[3];
    const float* bk  = (const float*)d_in[4];
    const float* Wv  = (const float*)d_in[5];
    const float* bv  = (const float*)d_in[6];
    const float* Wo  = (const float*)d_in[7];
    const float* bo  = (const float*)d_in[8];
    const float* gqs = (const float*)d_in[9];
    const float* gqb = (const float*)d_in[10];
    const float* gks = (const float*)d_in[11];
    const float* gkb = (const float*)d_in[12];
    const float* gvs = (const float*)d_in[13];
    const float* gvb = (const float*)d_in[14];

    const size_t NEL  = (size_t)NB * HWPX * CH;   // 8388608
    const size_t XHB  = NEL * 2;                  // bf16 Xh / O buffer
    const size_t F8B  = NEL;                      // fp8 buffers
    const size_t WTB  = 4 * 65536 * 2;
    const size_t BIASB = 4 * 256 * 4;
    size_t need = XHB + 3 * F8B + WTB + BIASB;
    if (ws_size < need) return;

    char* w = (char*)d_ws;
    u16*  Xh   = (u16*)(w);                       // [B][p][c] bf16; O after V proj
    u8*   Qf8  = (u8*)(w + XHB);
    u8*   Kf8  = (u8*)(w + XHB + F8B);
    u8*   Vf8  = (u8*)(w + XHB + 2 * F8B);
    u16*  Wt   = (u16*)(w + XHB + 3 * F8B);
    float* bias = (float*)(w + XHB + 3 * F8B + WTB);

    wprep<<<dim3(1024), dim3(256), 0, stream>>>(Wq, bq, gqs, gqb, Wk, bk, gks, gkb,
                                                Wv, bv, gvs, gvb, Wo, bo, Wt, bias);
    gn_kernel<<<dim3(1024), dim3(256), 0, stream>>>(x, Xh);

    // Q -> fp8 [p][d] (interleaved); K -> fp8 kv-blocked; V -> fp8 kv-blocked
    gemm_nt<0><<<dim3(4, 512), dim3(256), 0, stream>>>(Xh, Wt,           bias,       Qf8, nullptr, nullptr);
    gemm_nt<3><<<dim3(4, 512), dim3(256), 0, stream>>>(Xh, Wt + 65536,   bias + 256, Kf8, nullptr, nullptr);
    gemm_nt<1><<<dim3(512, 4), dim3(256), 0, stream>>>(Wt + 131072, Xh,  bias + 512, Vf8, nullptr, nullptr);
    // attention (writes bf16 O into Xh; Xh dead after V proj)
    attn<<<dim3(256), dim3(512), 0, stream>>>(Qf8, Kf8, Vf8, Xh);
    // out = x + Wo^T O + bo
    gemm_nt<2><<<dim3(512, 4), dim3(256), 0, stream>>>(Wt + 196608, Xh,  bias + 768, nullptr, (float*)d_out, x);
}

// Round 13
// 116.326 us; speedup vs baseline: 1.3596x; 1.1385x over previous
//
#include <hip/hip_runtime.h>
#include <stdint.h>

// B=32, C=256, H=W=32 (HW=1024), GROUPS=32, EPS=1e-5.
// K0 wprep : fp8 weights W8[768][256] (gs folded, NO q-scale: subnormal hazard);
//            Wt_o bf16; bias f32 (q-bias pre-scaled by log2e/16).
// K1 gn    : single-read groupnorm -> Xq8[p][c] FP8.
// K2 qkv   : ONE fused GEMM, fp8 x fp8 (mfma_f32_16x16x32_fp8_fp8), 128x128 tile,
//            K=256 single-stage (A+B = 64KB LDS, 2 blocks/CU). Q/K stored in a
//            permuted d-basis (phys = lr*8+nt <- logical nt*16+lr, same for both:
//            dot invariant), 8B stores. V -> kv-blocked [T][c][32], byte stores.
//            Q scaled by log2e/16 in epilogue.
// K3 attn  : unchanged r12 kernel (FP8, 8 waves = 4q x 2kv-halves, in-LDS merge).
// K4 gemm_out: out = x + Wo^T O + bo (fp32), bf16 operands (unchanged).

#define NB 32
#define CH 256
#define HWPX 1024

typedef __bf16 bf16x8 __attribute__((ext_vector_type(8)));
typedef float f32x4 __attribute__((ext_vector_type(4)));
typedef float f32x16 __attribute__((ext_vector_type(16)));
typedef unsigned short u16;
typedef unsigned char u8;
typedef unsigned int u32;
typedef u16 u16x8 __attribute__((ext_vector_type(8)));
typedef u32 u32x2 __attribute__((ext_vector_type(2)));

__device__ __forceinline__ u16 f2bf(float f) {
    __bf16 h = (__bf16)f;
    return __builtin_bit_cast(u16, h);
}
__device__ __forceinline__ bf16x8 ldb8(const u16* p) {
    return __builtin_bit_cast(bf16x8, *(const u16x8*)p);
}
__device__ __forceinline__ u32 pkfp8(float a, float b, float c, float d) {
    int w = __builtin_amdgcn_cvt_pk_fp8_f32(a, b, 0, false);
    w = __builtin_amdgcn_cvt_pk_fp8_f32(c, d, w, true);
    return (u32)w;
}
__device__ __forceinline__ void gld_lds16(const u8* g, u8* l) {
    __builtin_amdgcn_global_load_lds(
        (const __attribute__((address_space(1))) void*)g,
        (__attribute__((address_space(3))) void*)l, 16, 0, 0);
}

// ---------------- K0: weight prep ----------------
__global__ __launch_bounds__(256) void wprep(
    const float* __restrict__ Wq, const float* __restrict__ bq,
    const float* __restrict__ gqs, const float* __restrict__ gqb,
    const float* __restrict__ Wk, const float* __restrict__ bk,
    const float* __restrict__ gks, const float* __restrict__ gkb,
    const float* __restrict__ Wv, const float* __restrict__ bv,
    const float* __restrict__ gvs, const float* __restrict__ gvb,
    const float* __restrict__ Wo, const float* __restrict__ bo,
    u16* __restrict__ Wt, u8* __restrict__ W8, float* __restrict__ bias)
{
    int m = blockIdx.x >> 8;
    int d = blockIdx.x & 255;
    int c = threadIdx.x;
    const float *W, *bb, *gs, *gb; float scale;
    const float QSC = 0.09016844005556021f;   // log2(e)/16
    if (m == 0)      { W = Wq; bb = bq; gs = gqs; gb = gqb; scale = QSC; }
    else if (m == 1) { W = Wk; bb = bk; gs = gks; gb = gkb; scale = 1.f; }
    else if (m == 2) { W = Wv; bb = bv; gs = gvs; gb = gvb; scale = 1.f; }
    else             { W = Wo; bb = bo; gs = nullptr; gb = nullptr; scale = 1.f; }
    float w   = W[c * 256 + d];
    float gsc = gs ? gs[c] : 1.f;
    float gbc = gb ? gb[c] : 0.f;
    if (m == 3) {
        Wt[d * 256 + c] = f2bf(w);
    } else {
        float ws = w * gsc;                 // scale NOT folded (fp8 subnormal hazard)
        int q = __builtin_amdgcn_cvt_pk_fp8_f32(ws, ws, 0, false);
        W8[(size_t)(m * 256 + d) * 256 + c] = (u8)(q & 0xff);
    }
    __shared__ float red[256];
    red[c] = gbc * w;
    __syncthreads();
    for (int s = 128; s > 0; s >>= 1) { if (c < s) red[c] += red[c + s]; __syncthreads(); }
    if (c == 0) bias[m * 256 + d] = (bb[d] + red[0]) * scale;
}

// ---------------- K1: groupnorm, single x read -> fp8 ----------------
__global__ __launch_bounds__(256) void gn_kernel(const float* __restrict__ x,
                                                 u8* __restrict__ Xq8)
{
    int blk = blockIdx.x;
    int b = blk >> 5, g = blk & 31;
    const float* base = x + (size_t)(b * 256 + g * 8) * 1024;
    int t = threadIdx.x;
    float v[32];
    float s = 0.f, s2 = 0.f;
    #pragma unroll
    for (int j = 0; j < 8; j++) {
        #pragma unroll
        for (int pi = 0; pi < 4; pi++) {
            float val = base[j * 1024 + pi * 256 + t];
            v[j * 4 + pi] = val;
            s += val; s2 += val * val;
        }
    }
    __shared__ float rs[256], rq[256];
    rs[t] = s; rq[t] = s2;
    __syncthreads();
    for (int k = 128; k > 0; k >>= 1) {
        if (t < k) { rs[t] += rs[t + k]; rq[t] += rq[t + k]; }
        __syncthreads();
    }
    float mu  = rs[0] * (1.f / 8192.f);
    float var = rq[0] * (1.f / 8192.f) - mu * mu;
    float rv  = rsqrtf(var + 1e-5f);
    u8* outp = Xq8 + (size_t)b * (HWPX * CH) + g * 8;
    #pragma unroll
    for (int pi = 0; pi < 4; pi++) {
        int p = pi * 256 + t;
        u32 lo = pkfp8((v[0 * 4 + pi] - mu) * rv, (v[1 * 4 + pi] - mu) * rv,
                       (v[2 * 4 + pi] - mu) * rv, (v[3 * 4 + pi] - mu) * rv);
        u32 hi = pkfp8((v[4 * 4 + pi] - mu) * rv, (v[5 * 4 + pi] - mu) * rv,
                       (v[6 * 4 + pi] - mu) * rv, (v[7 * 4 + pi] - mu) * rv);
        u32x2 pk = { lo, hi };
        *(u32x2*)(outp + (size_t)p * 256) = pk;
    }
}

// ---------------- K2: fused QKV GEMM (fp8 x fp8) ----------------
// grid (256, 6): by = 128-row block of pixels, bx = 128-col block of [Q|K|V].
// 128x128 tile, K=256 single-stage; 4 waves, wave = 32 rows x 128 cols.
__global__ __launch_bounds__(256) void qkv_gemm(
    const u8* __restrict__ X8, const u8* __restrict__ W8,
    const float* __restrict__ bias,
    u8* __restrict__ Qf8, u8* __restrict__ Kf8, u8* __restrict__ Vf8)
{
    __shared__ __align__(16) u8 At[128 * 256];
    __shared__ __align__(16) u8 Bt[128 * 256];
    int tid = threadIdx.x;
    int by = blockIdx.x, bx = blockIdx.y;
    int mat = bx >> 1, half = bx & 1;
    int p0 = by * 128;

    const u8* Asrc = X8 + (size_t)p0 * 256;
    const u8* Bsrc = W8 + (size_t)bx * 128 * 256;
    #pragma unroll
    for (int i = 0; i < 8; i++) {
        int G = i * 256 + tid;
        int row = G >> 4, g16 = G & 15;
        int soff = row * 256 + ((g16 ^ (row & 7)) << 4);
        gld_lds16(Asrc + soff, At + (size_t)G * 16);
        gld_lds16(Bsrc + soff, Bt + (size_t)G * 16);
    }

    int lane = tid & 63, w = tid >> 6;
    int lr = lane & 15, hk = lane >> 4;
    int sub = (hk & 1) * 8;
    __syncthreads();

    f32x4 acc[2][8] = {};
    #pragma unroll
    for (int kk = 0; kk < 8; kk++) {
        int g16 = kk * 2 + (hk >> 1);
        long af[2], bfr[8];
        #pragma unroll
        for (int mf = 0; mf < 2; mf++) {
            int row = w * 32 + mf * 16 + lr;
            af[mf] = *(const long*)(At + row * 256 + ((g16 ^ (row & 7)) << 4) + sub);
        }
        #pragma unroll
        for (int nt = 0; nt < 8; nt++) {
            int row = nt * 16 + lr;
            bfr[nt] = *(const long*)(Bt + row * 256 + ((g16 ^ (row & 7)) << 4) + sub);
        }
        #pragma unroll
        for (int mf = 0; mf < 2; mf++)
            #pragma unroll
            for (int nt = 0; nt < 8; nt++)
                acc[mf][nt] = __builtin_amdgcn_mfma_f32_16x16x32_fp8_fp8(
                    af[mf], bfr[nt], acc[mf][nt], 0, 0, 0);
    }

    const float QSC = 0.09016844005556021f;
    float scale = (mat == 0) ? QSC : 1.f;
    const float* bs = bias + mat * 256 + half * 128;

    #pragma unroll
    for (int mf = 0; mf < 2; mf++) {
        #pragma unroll
        for (int j = 0; j < 4; j++) {
            int p = p0 + w * 32 + mf * 16 + (hk << 2) + j;
            if (mat < 2) {
                // permuted d-basis: phys e = lr*8+nt holds logical d = nt*16+lr
                u32 lo = pkfp8(acc[mf][0][j] * scale + bs[0 * 16 + lr],
                               acc[mf][1][j] * scale + bs[1 * 16 + lr],
                               acc[mf][2][j] * scale + bs[2 * 16 + lr],
                               acc[mf][3][j] * scale + bs[3 * 16 + lr]);
                u32 hi = pkfp8(acc[mf][4][j] * scale + bs[4 * 16 + lr],
                               acc[mf][5][j] * scale + bs[5 * 16 + lr],
                               acc[mf][6][j] * scale + bs[6 * 16 + lr],
                               acc[mf][7][j] * scale + bs[7 * 16 + lr]);
                u32x2 val = { lo, hi };
                if (mat == 0) {
                    *(u32x2*)(Qf8 + (size_t)p * 256 + half * 128 + lr * 8) = val;
                } else {
                    int pb = p & 1023;
                    size_t off = (size_t)(p >> 10) * 262144 + (size_t)(pb >> 5) * 8192
                               + (size_t)(half * 8 + (lr >> 1)) * 512
                               + (pb & 31) * 16 + (lr & 1) * 8;
                    *(u32x2*)(Kf8 + off) = val;
                }
            } else {
                // V kv-blocked [b][T][c][p&31], natural c, byte stores
                int pb = p & 1023;
                size_t base = (size_t)(p >> 10) * 262144 + (size_t)(pb >> 5) * 8192 + (pb & 31);
                #pragma unroll
                for (int nt = 0; nt < 8; nt++) {
                    int c = half * 128 + nt * 16 + lr;
                    float vv = acc[mf][nt][j] + bs[nt * 16 + lr];
                    int q = __builtin_amdgcn_cvt_pk_fp8_f32(vv, vv, 0, false);
                    Vf8[base + (size_t)c * 32] = (u8)(q & 0xff);
                }
            }
        }
    }
}

// ---------------- K3: FP8 flash attention, in-block kv-split (r12, unchanged) ----------------
__global__ __launch_bounds__(512, 2) void attn(
    const u8* __restrict__ Qf8, const u8* __restrict__ Kf8,
    const u8* __restrict__ Vf8, u16* __restrict__ O)
{
    __shared__ __align__(16) u8 SM[67584];

    int tid = threadIdx.x;
    int lane = tid & 63, wave = tid >> 6;
    int wq = wave & 3, h = wave >> 2;
    int bid = blockIdx.x;
    int b  = (bid & 7) * 4 + (bid >> 6);   // XCD x hosts batches 4x..4x+3
    int qb = (bid >> 3) & 7;
    int q0 = qb * 128 + wq * 32;
    int lq = lane & 31, hi = lane >> 5;

    const u8* Qb = Qf8 + (size_t)b * 262144;
    const u8* Kb = Kf8 + (size_t)b * 262144 + (size_t)h * 131072;
    const u8* Vb = Vf8 + (size_t)b * 262144 + (size_t)h * 131072;

    u8* Kl0 = SM + (size_t)(h * 2) * 8192;
    u8* Kl1 = SM + (size_t)(h * 2 + 1) * 8192;
    u8* Vl0 = SM + 32768 + (size_t)(h * 2) * 8192;
    u8* Vl1 = SM + 32768 + (size_t)(h * 2 + 1) * 8192;
    float* ml = (float*)(SM + 65536);

    long qf[16];
    #pragma unroll
    for (int f = 0; f < 16; f++)
        qf[f] = *(const long*)(Qb + (size_t)(q0 + lq) * 256 + f * 16 + hi * 8);

    f32x16 oa[8] = {};
    float m_run = -1e30f, l_run = 0.f;

    #pragma unroll
    for (int i = 0; i < 2; i++) {
        int Gs = (i * 256 + wq * 64 + lane) << 4;
        int Gd = (i * 256 + wq * 64) << 4;
        gld_lds16(Kb + Gs, Kl0 + Gd);
        gld_lds16(Vb + Gs, Vl0 + Gd);
    }
    __syncthreads();

    for (int t = 0; t < 16; ++t) {
        u8* kcur = (t & 1) ? Kl1 : Kl0;
        u8* vcur = (t & 1) ? Vl1 : Vl0;
        if (t < 15) {
            u8* knxt = (t & 1) ? Kl0 : Kl1;
            u8* vnxt = (t & 1) ? Vl0 : Vl1;
            const u8* ks = Kb + (size_t)(t + 1) * 8192;
            const u8* vs = Vb + (size_t)(t + 1) * 8192;
            #pragma unroll
            for (int i = 0; i < 2; i++) {
                int Gs = (i * 256 + wq * 64 + lane) << 4;
                int Gd = (i * 256 + wq * 64) << 4;
                gld_lds16(ks + Gs, knxt + Gd);
                gld_lds16(vs + Gs, vnxt + Gd);
            }
        }

        f32x16 s0 = {}, s1 = {};
        #pragma unroll
        for (int ff = 0; ff < 8; ff++) {
            long k0 = *(const long*)(kcur + (2 * ff) * 512 + lq * 16 + hi * 8);
            s0 = __builtin_amdgcn_mfma_f32_32x32x16_fp8_fp8(k0, qf[2 * ff], s0, 0, 0, 0);
            long k1 = *(const long*)(kcur + (2 * ff + 1) * 512 + lq * 16 + hi * 8);
            s1 = __builtin_amdgcn_mfma_f32_32x32x16_fp8_fp8(k1, qf[2 * ff + 1], s1, 0, 0, 0);
        }

        long vf[16];
        #pragma unroll
        for (int ct = 0; ct < 8; ct++) {
            vf[2 * ct]     = *(const long*)(vcur + ct * 1024 + lq * 16 + hi * 8);
            vf[2 * ct + 1] = *(const long*)(vcur + ct * 1024 + 512 + lq * 16 + hi * 8);
        }

        float s[16];
        #pragma unroll
        for (int r = 0; r < 16; r++) s[r] = s0[r] + s1[r];

        float m01 = fmaxf(s[0], s[1]),   m23 = fmaxf(s[2], s[3]);
        float m45 = fmaxf(s[4], s[5]),   m67 = fmaxf(s[6], s[7]);
        float m89 = fmaxf(s[8], s[9]),   mab = fmaxf(s[10], s[11]);
        float mcd = fmaxf(s[12], s[13]), mef = fmaxf(s[14], s[15]);
        float mloc = fmaxf(fmaxf(fmaxf(m01, m23), fmaxf(m45, m67)),
                           fmaxf(fmaxf(m89, mab), fmaxf(mcd, mef)));
        if (!__all(mloc - m_run <= 4.f)) {
            float mo = fmaxf(mloc, __shfl_xor(mloc, 32));
            float mn = fmaxf(m_run, mo);
            float sc = exp2f(m_run - mn);
            m_run = mn;
            l_run *= sc;
            #pragma unroll
            for (int ct = 0; ct < 8; ct++) {
                #pragma unroll
                for (int r = 0; r < 16; r++) oa[ct][r] *= sc;
            }
        }
        float p[16];
        #pragma unroll
        for (int r = 0; r < 16; r++) p[r] = exp2f(s[r] - m_run);
        l_run += (((p[0]+p[1])+(p[2]+p[3]))+((p[4]+p[5])+(p[6]+p[7])))
               + (((p[8]+p[9])+(p[10]+p[11]))+((p[12]+p[13])+(p[14]+p[15])));

        u32 a  = pkfp8(p[0],  p[1],  p[2],  p[3]);
        u32 bb = pkfp8(p[4],  p[5],  p[6],  p[7]);
        u32 c  = pkfp8(p[8],  p[9],  p[10], p[11]);
        u32 d  = pkfp8(p[12], p[13], p[14], p[15]);
        u32 xa = (u32)__shfl_xor((int)a, 32),  xb = (u32)__shfl_xor((int)bb, 32);
        u32 xc = (u32)__shfl_xor((int)c, 32),  xd = (u32)__shfl_xor((int)d, 32);
        u32x2 f0 = { hi ? xb : a, hi ? bb : xa };
        u32x2 f1 = { hi ? xd : c, hi ? d  : xc };
        long p0 = __builtin_bit_cast(long, f0);
        long p1 = __builtin_bit_cast(long, f1);

        #pragma unroll
        for (int ct = 0; ct < 8; ct++) {
            oa[ct] = __builtin_amdgcn_mfma_f32_32x32x16_fp8_fp8(vf[2 * ct],     p0, oa[ct], 0, 0, 0);
            oa[ct] = __builtin_amdgcn_mfma_f32_32x32x16_fp8_fp8(vf[2 * ct + 1], p1, oa[ct], 0, 0, 0);
        }
        __syncthreads();
    }

    float lt = l_run + __shfl_xor(l_run, 32);
    if (hi == 0) {
        ml[(wave * 32 + lq) * 2]     = m_run;
        ml[(wave * 32 + lq) * 2 + 1] = lt;
    }
    __syncthreads();
    int pw = wave ^ 4;
    float m_o = ml[(pw * 32 + lq) * 2];
    float l_o = ml[(pw * 32 + lq) * 2 + 1];
    float mm  = fmaxf(m_run, m_o);
    float denom = exp2f(m_run - mm) * lt + exp2f(m_o - mm) * l_o;
    float myw = exp2f(m_run - mm) / denom;
    #pragma unroll
    for (int ct = 0; ct < 8; ct++) {
        #pragma unroll
        for (int r = 0; r < 16; r++) oa[ct][r] *= myw;
    }

    float* mbuf = (float*)SM;
    u16* Ob = O + (size_t)b * (HWPX * CH) + (size_t)(q0 + lq) * 256;
    for (int ch = 0; ch < 2; ++ch) {
        if (h == 1) {
            #pragma unroll
            for (int ctl = 0; ctl < 4; ++ctl) {
                int ct = ch * 4 + ctl;
                #pragma unroll
                for (int r = 0; r < 16; ++r) {
                    int crow = (r & 3) + 8 * (r >> 2) + 4 * hi;
                    mbuf[((wq * 4 + ctl) * 32 + crow) * 32 + lq] = oa[ct][r];
                }
            }
        }
        __syncthreads();
        if (h == 0) {
            #pragma unroll
            for (int ctl = 0; ctl < 4; ++ctl) {
                int ct = ch * 4 + ctl;
                #pragma unroll
                for (int rg = 0; rg < 4; ++rg) {
                    u16* dst = Ob + 32 * ct + 8 * rg + 4 * hi;
                    #pragma unroll
                    for (int v = 0; v < 4; ++v) {
                        int r = rg * 4 + v;
                        int crow = v + 8 * rg + 4 * hi;
                        float sum = oa[ct][r] + mbuf[((wq * 4 + ctl) * 32 + crow) * 32 + lq];
                        dst[v] = f2bf(sum);
                    }
                }
            }
        }
        __syncthreads();
    }
}

// ---------------- K4: final GEMM (bf16), out = x + Wo^T O + bo ----------------
__global__ __launch_bounds__(256) void gemm_out(
    const u16* __restrict__ A, const u16* __restrict__ Bm,
    const float* __restrict__ bias,
    float* __restrict__ Cf, const float* __restrict__ xres)
{
    __shared__ __align__(16) u16 Bt[64 * 256];
    int tid = threadIdx.x;
    int lane = tid & 63, wave = tid >> 6;
    int m0 = blockIdx.y * 64 + wave * 16;
    int n0 = blockIdx.x * 64;

    #pragma unroll
    for (int i = 0; i < 8; i++) {
        int G = i * 256 + tid;
        int row = G >> 5, g = G & 31;
        const u16* src = Bm + (size_t)(n0 + row) * 256 + ((g ^ (row & 7)) << 3);
        gld_lds16((const u8*)src, (u8*)(Bt + (size_t)(i * 256 + wave * 64) * 8));
    }

    int lr = lane & 15, hk = lane >> 4, lk = hk * 8;
    const u16* Ap = A + (size_t)(m0 + lr) * 256 + lk;
    bf16x8 af[8];
    #pragma unroll
    for (int kk = 0; kk < 8; kk++) af[kk] = ldb8(Ap + kk * 32);

    __syncthreads();

    f32x4 acc[4] = {};
    bf16x8 b0[4], b1[4];
    #pragma unroll
    for (int nt = 0; nt < 4; nt++) {
        int row = nt * 16 + lr;
        b0[nt] = ldb8(Bt + (size_t)(row * 32 + (hk ^ (row & 7))) * 8);
    }
    #pragma unroll
    for (int kk = 0; kk < 8; kk++) {
        if (kk & 1) {
            if (kk < 7) {
                #pragma unroll
                for (int nt = 0; nt < 4; nt++) {
                    int row = nt * 16 + lr;
                    b0[nt] = ldb8(Bt + (size_t)(row * 32 + (((kk + 1) * 4 + hk) ^ (row & 7))) * 8);
                }
            }
            #pragma unroll
            for (int nt = 0; nt < 4; nt++)
                acc[nt] = __builtin_amdgcn_mfma_f32_16x16x32_bf16(af[kk], b1[nt], acc[nt], 0, 0, 0);
        } else {
            #pragma unroll
            for (int nt = 0; nt < 4; nt++) {
                int row = nt * 16 + lr;
                b1[nt] = ldb8(Bt + (size_t)(row * 32 + (((kk + 1) * 4 + hk) ^ (row & 7))) * 8);
            }
            #pragma unroll
            for (int nt = 0; nt < 4; nt++)
                acc[nt] = __builtin_amdgcn_mfma_f32_16x16x32_bf16(af[kk], b0[nt], acc[nt], 0, 0, 0);
        }
    }
    int rbase = m0 + (hk << 2);
    #pragma unroll
    for (int nt = 0; nt < 4; nt++) {
        int col = n0 + nt * 16 + lr;
        int b = col >> 10, p = col & 1023;
        #pragma unroll
        for (int j = 0; j < 4; j++) {
            int row = rbase + j;
            float v = acc[nt][j] + bias[row];
            size_t off = (size_t)b * (CH * HWPX) + (size_t)row * 1024 + p;
            Cf[off] = v + xres[off];
        }
    }
}

// ---------------- host launch ----------------
extern "C" void kernel_launch(void* const* d_in, const int* in_sizes, int n_in,
                              void* d_out, int out_size, void* d_ws, size_t ws_size,
                              hipStream_t stream)
{
    const float* x   = (const float*)d_in[0];
    const float* Wq  = (const float*)d_in[1];
    const float* bq  = (const float*)d_in[2];
    const float* Wk  = (const float*)d_in[3];
    const float* bk  = (const float*)d_in[4];
    const float* Wv  = (const float*)d_in[5];
    const float* bv  = (const float*)d_in[6];
    const float* Wo  = (const float*)d_in[7];
    const float* bo  = (const float*)d_in[8];
    const float* gqs = (const float*)d_in[9];
    const float* gqb = (const float*)d_in[10];
    const float* gks = (const float*)d_in[11];
    const float* gkb = (const float*)d_in[12];
    const float* gvs = (const float*)d_in[13];
    const float* gvb = (const float*)d_in[14];

    const size_t NEL  = (size_t)NB * HWPX * CH;   // 8388608
    const size_t F8B  = NEL;                      // fp8 buffers (8.4 MB)
    const size_t OB   = NEL * 2;                  // bf16 O buffer (16.8 MB)
    const size_t WTB  = 65536 * 2;                // Wt_o bf16
    const size_t W8B  = 768 * 256;                // fp8 weights
    const size_t BIASB = 4 * 256 * 4;
    size_t need = 4 * F8B + OB + WTB + W8B + BIASB;
    if (ws_size < need) return;

    char* w = (char*)d_ws;
    u8*   Xq8  = (u8*)(w);
    u8*   Qf8  = (u8*)(w + F8B);
    u8*   Kf8  = (u8*)(w + 2 * F8B);
    u8*   Vf8  = (u8*)(w + 3 * F8B);
    u16*  O    = (u16*)(w + 4 * F8B);
    u16*  Wt   = (u16*)(w + 4 * F8B + OB);
    u8*   W8   = (u8*)(w + 4 * F8B + OB + WTB);
    float* bias = (float*)(w + 4 * F8B + OB + WTB + W8B);

    wprep<<<dim3(1024), dim3(256), 0, stream>>>(Wq, bq, gqs, gqb, Wk, bk, gks, gkb,
                                                Wv, bv, gvs, gvb, Wo, bo, Wt, W8, bias);
    gn_kernel<<<dim3(1024), dim3(256), 0, stream>>>(x, Xq8);
    qkv_gemm<<<dim3(256, 6), dim3(256), 0, stream>>>(Xq8, W8, bias, Qf8, Kf8, Vf8);
    attn<<<dim3(256), dim3(512), 0, stream>>>(Qf8, Kf8, Vf8, O);
    gemm_out<<<dim3(512, 4), dim3(256), 0, stream>>>(Wt, O, bias + 768, (float*)d_out, x);
}

// Round 14
// 106.279 us; speedup vs baseline: 1.4882x; 1.0945x over previous
//
#include <hip/hip_runtime.h>
#include <stdint.h>

// B=32, C=256, H=W=32 (HW=1024), GROUPS=32, EPS=1e-5.
// K0 wprep : fp8 weights W8[768][256] (gs folded); Wt_o bf16; bias f32.
// K1 gn    : single-read groupnorm -> Xq8[p][c] FP8.
// K2 qkv   : fused QKV GEMM fp8xfp8, 128x128 tile. Q/K permuted-d 8B stores;
//            V kv-blocked [T][c][32] DWORD stores (4 consecutive p packed).
// K3 attn  : FP8 flash attn (r12 structure); P-pack via v_permlane32_swap_b32
//            (VALU) instead of __shfl_xor (LDS pipe) -> kills the 4.19M
//            SQ_LDS_BANK_CONFLICT cycles.
// K4 gemm_out: out = x + Wo^T O + bo (fp32), bf16 operands.

#define NB 32
#define CH 256
#define HWPX 1024

typedef __bf16 bf16x8 __attribute__((ext_vector_type(8)));
typedef float f32x4 __attribute__((ext_vector_type(4)));
typedef float f32x16 __attribute__((ext_vector_type(16)));
typedef unsigned short u16;
typedef unsigned char u8;
typedef unsigned int u32;
typedef u16 u16x8 __attribute__((ext_vector_type(8)));
typedef u32 u32x2 __attribute__((ext_vector_type(2)));

__device__ __forceinline__ u16 f2bf(float f) {
    __bf16 h = (__bf16)f;
    return __builtin_bit_cast(u16, h);
}
__device__ __forceinline__ bf16x8 ldb8(const u16* p) {
    return __builtin_bit_cast(bf16x8, *(const u16x8*)p);
}
__device__ __forceinline__ u32 pkfp8(float a, float b, float c, float d) {
    int w = __builtin_amdgcn_cvt_pk_fp8_f32(a, b, 0, false);
    w = __builtin_amdgcn_cvt_pk_fp8_f32(c, d, w, true);
    return (u32)w;
}
__device__ __forceinline__ void gld_lds16(const u8* g, u8* l) {
    __builtin_amdgcn_global_load_lds(
        (const __attribute__((address_space(1))) void*)g,
        (__attribute__((address_space(3))) void*)l, 16, 0, 0);
}

// ---------------- K0: weight prep ----------------
__global__ __launch_bounds__(256) void wprep(
    const float* __restrict__ Wq, const float* __restrict__ bq,
    const float* __restrict__ gqs, const float* __restrict__ gqb,
    const float* __restrict__ Wk, const float* __restrict__ bk,
    const float* __restrict__ gks, const float* __restrict__ gkb,
    const float* __restrict__ Wv, const float* __restrict__ bv,
    const float* __restrict__ gvs, const float* __restrict__ gvb,
    const float* __restrict__ Wo, const float* __restrict__ bo,
    u16* __restrict__ Wt, u8* __restrict__ W8, float* __restrict__ bias)
{
    int m = blockIdx.x >> 8;
    int d = blockIdx.x & 255;
    int c = threadIdx.x;
    const float *W, *bb, *gs, *gb; float scale;
    const float QSC = 0.09016844005556021f;   // log2(e)/16
    if (m == 0)      { W = Wq; bb = bq; gs = gqs; gb = gqb; scale = QSC; }
    else if (m == 1) { W = Wk; bb = bk; gs = gks; gb = gkb; scale = 1.f; }
    else if (m == 2) { W = Wv; bb = bv; gs = gvs; gb = gvb; scale = 1.f; }
    else             { W = Wo; bb = bo; gs = nullptr; gb = nullptr; scale = 1.f; }
    float w   = W[c * 256 + d];
    float gsc = gs ? gs[c] : 1.f;
    float gbc = gb ? gb[c] : 0.f;
    if (m == 3) {
        Wt[d * 256 + c] = f2bf(w);
    } else {
        float ws = w * gsc;                 // scale NOT folded (fp8 subnormal hazard)
        int q = __builtin_amdgcn_cvt_pk_fp8_f32(ws, ws, 0, false);
        W8[(size_t)(m * 256 + d) * 256 + c] = (u8)(q & 0xff);
    }
    __shared__ float red[256];
    red[c] = gbc * w;
    __syncthreads();
    for (int s = 128; s > 0; s >>= 1) { if (c < s) red[c] += red[c + s]; __syncthreads(); }
    if (c == 0) bias[m * 256 + d] = (bb[d] + red[0]) * scale;
}

// ---------------- K1: groupnorm, single x read -> fp8 ----------------
__global__ __launch_bounds__(256) void gn_kernel(const float* __restrict__ x,
                                                 u8* __restrict__ Xq8)
{
    int blk = blockIdx.x;
    int b = blk >> 5, g = blk & 31;
    const float* base = x + (size_t)(b * 256 + g * 8) * 1024;
    int t = threadIdx.x;
    float v[32];
    float s = 0.f, s2 = 0.f;
    #pragma unroll
    for (int j = 0; j < 8; j++) {
        #pragma unroll
        for (int pi = 0; pi < 4; pi++) {
            float val = base[j * 1024 + pi * 256 + t];
            v[j * 4 + pi] = val;
            s += val; s2 += val * val;
        }
    }
    __shared__ float rs[256], rq[256];
    rs[t] = s; rq[t] = s2;
    __syncthreads();
    for (int k = 128; k > 0; k >>= 1) {
        if (t < k) { rs[t] += rs[t + k]; rq[t] += rq[t + k]; }
        __syncthreads();
    }
    float mu  = rs[0] * (1.f / 8192.f);
    float var = rq[0] * (1.f / 8192.f) - mu * mu;
    float rv  = rsqrtf(var + 1e-5f);
    u8* outp = Xq8 + (size_t)b * (HWPX * CH) + g * 8;
    #pragma unroll
    for (int pi = 0; pi < 4; pi++) {
        int p = pi * 256 + t;
        u32 lo = pkfp8((v[0 * 4 + pi] - mu) * rv, (v[1 * 4 + pi] - mu) * rv,
                       (v[2 * 4 + pi] - mu) * rv, (v[3 * 4 + pi] - mu) * rv);
        u32 hi = pkfp8((v[4 * 4 + pi] - mu) * rv, (v[5 * 4 + pi] - mu) * rv,
                       (v[6 * 4 + pi] - mu) * rv, (v[7 * 4 + pi] - mu) * rv);
        u32x2 pk = { lo, hi };
        *(u32x2*)(outp + (size_t)p * 256) = pk;
    }
}

// ---------------- K2: fused QKV GEMM (fp8 x fp8) ----------------
__global__ __launch_bounds__(256) void qkv_gemm(
    const u8* __restrict__ X8, const u8* __restrict__ W8,
    const float* __restrict__ bias,
    u8* __restrict__ Qf8, u8* __restrict__ Kf8, u8* __restrict__ Vf8)
{
    __shared__ __align__(16) u8 At[128 * 256];
    __shared__ __align__(16) u8 Bt[128 * 256];
    int tid = threadIdx.x;
    int by = blockIdx.x, bx = blockIdx.y;
    int mat = bx >> 1, half = bx & 1;
    int p0 = by * 128;

    const u8* Asrc = X8 + (size_t)p0 * 256;
    const u8* Bsrc = W8 + (size_t)bx * 128 * 256;
    #pragma unroll
    for (int i = 0; i < 8; i++) {
        int G = i * 256 + tid;
        int row = G >> 4, g16 = G & 15;
        int soff = row * 256 + ((g16 ^ (row & 7)) << 4);
        gld_lds16(Asrc + soff, At + (size_t)G * 16);
        gld_lds16(Bsrc + soff, Bt + (size_t)G * 16);
    }

    int lane = tid & 63, w = tid >> 6;
    int lr = lane & 15, hk = lane >> 4;
    int sub = (hk & 1) * 8;
    __syncthreads();

    f32x4 acc[2][8] = {};
    #pragma unroll
    for (int kk = 0; kk < 8; kk++) {
        int g16 = kk * 2 + (hk >> 1);
        long af[2], bfr[8];
        #pragma unroll
        for (int mf = 0; mf < 2; mf++) {
            int row = w * 32 + mf * 16 + lr;
            af[mf] = *(const long*)(At + row * 256 + ((g16 ^ (row & 7)) << 4) + sub);
        }
        #pragma unroll
        for (int nt = 0; nt < 8; nt++) {
            int row = nt * 16 + lr;
            bfr[nt] = *(const long*)(Bt + row * 256 + ((g16 ^ (row & 7)) << 4) + sub);
        }
        #pragma unroll
        for (int mf = 0; mf < 2; mf++)
            #pragma unroll
            for (int nt = 0; nt < 8; nt++)
                acc[mf][nt] = __builtin_amdgcn_mfma_f32_16x16x32_fp8_fp8(
                    af[mf], bfr[nt], acc[mf][nt], 0, 0, 0);
    }

    const float QSC = 0.09016844005556021f;
    float scale = (mat == 0) ? QSC : 1.f;
    const float* bs = bias + mat * 256 + half * 128;

    #pragma unroll
    for (int mf = 0; mf < 2; mf++) {
        if (mat < 2) {
            #pragma unroll
            for (int j = 0; j < 4; j++) {
                int p = p0 + w * 32 + mf * 16 + (hk << 2) + j;
                // permuted d-basis: phys e = lr*8+nt holds logical d = nt*16+lr
                u32 lo = pkfp8(acc[mf][0][j] * scale + bs[0 * 16 + lr],
                               acc[mf][1][j] * scale + bs[1 * 16 + lr],
                               acc[mf][2][j] * scale + bs[2 * 16 + lr],
                               acc[mf][3][j] * scale + bs[3 * 16 + lr]);
                u32 hi = pkfp8(acc[mf][4][j] * scale + bs[4 * 16 + lr],
                               acc[mf][5][j] * scale + bs[5 * 16 + lr],
                               acc[mf][6][j] * scale + bs[6 * 16 + lr],
                               acc[mf][7][j] * scale + bs[7 * 16 + lr]);
                u32x2 val = { lo, hi };
                if (mat == 0) {
                    *(u32x2*)(Qf8 + (size_t)p * 256 + half * 128 + lr * 8) = val;
                } else {
                    int pb = p & 1023;
                    size_t off = (size_t)(p >> 10) * 262144 + (size_t)(pb >> 5) * 8192
                               + (size_t)(half * 8 + (lr >> 1)) * 512
                               + (pb & 31) * 16 + (lr & 1) * 8;
                    *(u32x2*)(Kf8 + off) = val;
                }
            }
        } else {
            // V kv-blocked [b][T][c][32]: DWORD stores (4 consecutive p packed)
            int p = p0 + w * 32 + mf * 16 + (hk << 2);   // j = 0 base, 4-aligned
            int pb = p & 1023;
            size_t base = (size_t)(p >> 10) * 262144 + (size_t)(pb >> 5) * 8192 + (pb & 31);
            #pragma unroll
            for (int nt = 0; nt < 8; nt++) {
                int c = half * 128 + nt * 16 + lr;
                float bvv = bs[nt * 16 + lr];
                u32 wv = pkfp8(acc[mf][nt][0] + bvv, acc[mf][nt][1] + bvv,
                               acc[mf][nt][2] + bvv, acc[mf][nt][3] + bvv);
                *(u32*)(Vf8 + base + (size_t)c * 32) = wv;
            }
        }
    }
}

// ---------------- K3: FP8 flash attention, permlane P-pack ----------------
__global__ __launch_bounds__(512, 2) void attn(
    const u8* __restrict__ Qf8, const u8* __restrict__ Kf8,
    const u8* __restrict__ Vf8, u16* __restrict__ O)
{
    __shared__ __align__(16) u8 SM[67584];

    int tid = threadIdx.x;
    int lane = tid & 63, wave = tid >> 6;
    int wq = wave & 3, h = wave >> 2;
    int bid = blockIdx.x;
    int b  = (bid & 7) * 4 + (bid >> 6);   // XCD x hosts batches 4x..4x+3
    int qb = (bid >> 3) & 7;
    int q0 = qb * 128 + wq * 32;
    int lq = lane & 31, hi = lane >> 5;

    const u8* Qb = Qf8 + (size_t)b * 262144;
    const u8* Kb = Kf8 + (size_t)b * 262144 + (size_t)h * 131072;
    const u8* Vb = Vf8 + (size_t)b * 262144 + (size_t)h * 131072;

    u8* Kl0 = SM + (size_t)(h * 2) * 8192;
    u8* Kl1 = SM + (size_t)(h * 2 + 1) * 8192;
    u8* Vl0 = SM + 32768 + (size_t)(h * 2) * 8192;
    u8* Vl1 = SM + 32768 + (size_t)(h * 2 + 1) * 8192;
    float* ml = (float*)(SM + 65536);

    long qf[16];
    #pragma unroll
    for (int f = 0; f < 16; f++)
        qf[f] = *(const long*)(Qb + (size_t)(q0 + lq) * 256 + f * 16 + hi * 8);

    f32x16 oa[8] = {};
    float m_run = -1e30f, l_run = 0.f;

    #pragma unroll
    for (int i = 0; i < 2; i++) {
        int Gs = (i * 256 + wq * 64 + lane) << 4;
        int Gd = (i * 256 + wq * 64) << 4;
        gld_lds16(Kb + Gs, Kl0 + Gd);
        gld_lds16(Vb + Gs, Vl0 + Gd);
    }
    __syncthreads();

    for (int t = 0; t < 16; ++t) {
        u8* kcur = (t & 1) ? Kl1 : Kl0;
        u8* vcur = (t & 1) ? Vl1 : Vl0;
        if (t < 15) {
            u8* knxt = (t & 1) ? Kl0 : Kl1;
            u8* vnxt = (t & 1) ? Vl0 : Vl1;
            const u8* ks = Kb + (size_t)(t + 1) * 8192;
            const u8* vs = Vb + (size_t)(t + 1) * 8192;
            #pragma unroll
            for (int i = 0; i < 2; i++) {
                int Gs = (i * 256 + wq * 64 + lane) << 4;
                int Gd = (i * 256 + wq * 64) << 4;
                gld_lds16(ks + Gs, knxt + Gd);
                gld_lds16(vs + Gs, vnxt + Gd);
            }
        }

        f32x16 s0 = {}, s1 = {};
        #pragma unroll
        for (int ff = 0; ff < 8; ff++) {
            long k0 = *(const long*)(kcur + (2 * ff) * 512 + lq * 16 + hi * 8);
            s0 = __builtin_amdgcn_mfma_f32_32x32x16_fp8_fp8(k0, qf[2 * ff], s0, 0, 0, 0);
            long k1 = *(const long*)(kcur + (2 * ff + 1) * 512 + lq * 16 + hi * 8);
            s1 = __builtin_amdgcn_mfma_f32_32x32x16_fp8_fp8(k1, qf[2 * ff + 1], s1, 0, 0, 0);
        }

        long vf[16];
        #pragma unroll
        for (int ct = 0; ct < 8; ct++) {
            vf[2 * ct]     = *(const long*)(vcur + ct * 1024 + lq * 16 + hi * 8);
            vf[2 * ct + 1] = *(const long*)(vcur + ct * 1024 + 512 + lq * 16 + hi * 8);
        }

        float s[16];
        #pragma unroll
        for (int r = 0; r < 16; r++) s[r] = s0[r] + s1[r];

        float m01 = fmaxf(s[0], s[1]),   m23 = fmaxf(s[2], s[3]);
        float m45 = fmaxf(s[4], s[5]),   m67 = fmaxf(s[6], s[7]);
        float m89 = fmaxf(s[8], s[9]),   mab = fmaxf(s[10], s[11]);
        float mcd = fmaxf(s[12], s[13]), mef = fmaxf(s[14], s[15]);
        float mloc = fmaxf(fmaxf(fmaxf(m01, m23), fmaxf(m45, m67)),
                           fmaxf(fmaxf(m89, mab), fmaxf(mcd, mef)));
        if (!__all(mloc - m_run <= 4.f)) {
            float mo = fmaxf(mloc, __shfl_xor(mloc, 32));
            float mn = fmaxf(m_run, mo);
            float sc = exp2f(m_run - mn);
            m_run = mn;
            l_run *= sc;
            #pragma unroll
            for (int ct = 0; ct < 8; ct++) {
                #pragma unroll
                for (int r = 0; r < 16; r++) oa[ct][r] *= sc;
            }
        }
        float p[16];
        #pragma unroll
        for (int r = 0; r < 16; r++) p[r] = exp2f(s[r] - m_run);
        l_run += (((p[0]+p[1])+(p[2]+p[3]))+((p[4]+p[5])+(p[6]+p[7])))
               + (((p[8]+p[9])+(p[10]+p[11]))+((p[12]+p[13])+(p[14]+p[15])));

        // ---- pack P^T to fp8 B-fragments: permlane32_swap (VALU, no LDS) ----
        u32 a  = pkfp8(p[0],  p[1],  p[2],  p[3]);
        u32 bb = pkfp8(p[4],  p[5],  p[6],  p[7]);
        u32 c  = pkfp8(p[8],  p[9],  p[10], p[11]);
        u32 d  = pkfp8(p[12], p[13], p[14], p[15]);
        asm volatile("v_permlane32_swap_b32 %0, %1" : "+v"(a), "+v"(bb));
        asm volatile("v_permlane32_swap_b32 %0, %1" : "+v"(c), "+v"(d));
        u32x2 f0 = { a, bb };
        u32x2 f1 = { c, d };
        long p0 = __builtin_bit_cast(long, f0);
        long p1 = __builtin_bit_cast(long, f1);

        #pragma unroll
        for (int ct = 0; ct < 8; ct++) {
            oa[ct] = __builtin_amdgcn_mfma_f32_32x32x16_fp8_fp8(vf[2 * ct],     p0, oa[ct], 0, 0, 0);
            oa[ct] = __builtin_amdgcn_mfma_f32_32x32x16_fp8_fp8(vf[2 * ct + 1], p1, oa[ct], 0, 0, 0);
        }
        __syncthreads();
    }

    float lt = l_run + __shfl_xor(l_run, 32);
    if (hi == 0) {
        ml[(wave * 32 + lq) * 2]     = m_run;
        ml[(wave * 32 + lq) * 2 + 1] = lt;
    }
    __syncthreads();
    int pw = wave ^ 4;
    float m_o = ml[(pw * 32 + lq) * 2];
    float l_o = ml[(pw * 32 + lq) * 2 + 1];
    float mm  = fmaxf(m_run, m_o);
    float denom = exp2f(m_run - mm) * lt + exp2f(m_o - mm) * l_o;
    float myw = exp2f(m_run - mm) / denom;
    #pragma unroll
    for (int ct = 0; ct < 8; ct++) {
        #pragma unroll
        for (int r = 0; r < 16; r++) oa[ct][r] *= myw;
    }

    float* mbuf = (float*)SM;
    u16* Ob = O + (size_t)b * (HWPX * CH) + (size_t)(q0 + lq) * 256;
    for (int ch = 0; ch < 2; ++ch) {
        if (h == 1) {
            #pragma unroll
            for (int ctl = 0; ctl < 4; ++ctl) {
                int ct = ch * 4 + ctl;
                #pragma unroll
                for (int r = 0; r < 16; ++r) {
                    int crow = (r & 3) + 8 * (r >> 2) + 4 * hi;
                    mbuf[((wq * 4 + ctl) * 32 + crow) * 32 + lq] = oa[ct][r];
                }
            }
        }
        __syncthreads();
        if (h == 0) {
            #pragma unroll
            for (int ctl = 0; ctl < 4; ++ctl) {
                int ct = ch * 4 + ctl;
                #pragma unroll
                for (int rg = 0; rg < 4; ++rg) {
                    u16* dst = Ob + 32 * ct + 8 * rg + 4 * hi;
                    #pragma unroll
                    for (int v = 0; v < 4; ++v) {
                        int r = rg * 4 + v;
                        int crow = v + 8 * rg + 4 * hi;
                        float sum = oa[ct][r] + mbuf[((wq * 4 + ctl) * 32 + crow) * 32 + lq];
                        dst[v] = f2bf(sum);
                    }
                }
            }
        }
        __syncthreads();
    }
}

// ---------------- K4: final GEMM (bf16), out = x + Wo^T O + bo ----------------
__global__ __launch_bounds__(256) void gemm_out(
    const u16* __restrict__ A, const u16* __restrict__ Bm,
    const float* __restrict__ bias,
    float* __restrict__ Cf, const float* __restrict__ xres)
{
    __shared__ __align__(16) u16 Bt[64 * 256];
    int tid = threadIdx.x;
    int lane = tid & 63, wave = tid >> 6;
    int m0 = blockIdx.y * 64 + wave * 16;
    int n0 = blockIdx.x * 64;

    #pragma unroll
    for (int i = 0; i < 8; i++) {
        int G = i * 256 + tid;
        int row = G >> 5, g = G & 31;
        const u16* src = Bm + (size_t)(n0 + row) * 256 + ((g ^ (row & 7)) << 3);
        gld_lds16((const u8*)src, (u8*)(Bt + (size_t)(i * 256 + wave * 64) * 8));
    }

    int lr = lane & 15, hk = lane >> 4, lk = hk * 8;
    const u16* Ap = A + (size_t)(m0 + lr) * 256 + lk;
    bf16x8 af[8];
    #pragma unroll
    for (int kk = 0; kk < 8; kk++) af[kk] = ldb8(Ap + kk * 32);

    __syncthreads();

    f32x4 acc[4] = {};
    bf16x8 b0[4], b1[4];
    #pragma unroll
    for (int nt = 0; nt < 4; nt++) {
        int row = nt * 16 + lr;
        b0[nt] = ldb8(Bt + (size_t)(row * 32 + (hk ^ (row & 7))) * 8);
    }
    #pragma unroll
    for (int kk = 0; kk < 8; kk++) {
        if (kk & 1) {
            if (kk < 7) {
                #pragma unroll
                for (int nt = 0; nt < 4; nt++) {
                    int row = nt * 16 + lr;
                    b0[nt] = ldb8(Bt + (size_t)(row * 32 + (((kk + 1) * 4 + hk) ^ (row & 7))) * 8);
                }
            }
            #pragma unroll
            for (int nt = 0; nt < 4; nt++)
                acc[nt] = __builtin_amdgcn_mfma_f32_16x16x32_bf16(af[kk], b1[nt], acc[nt], 0, 0, 0);
        } else {
            #pragma unroll
            for (int nt = 0; nt < 4; nt++) {
                int row = nt * 16 + lr;
                b1[nt] = ldb8(Bt + (size_t)(row * 32 + (((kk + 1) * 4 + hk) ^ (row & 7))) * 8);
            }
            #pragma unroll
            for (int nt = 0; nt < 4; nt++)
                acc[nt] = __builtin_amdgcn_mfma_f32_16x16x32_bf16(af[kk], b0[nt], acc[nt], 0, 0, 0);
        }
    }
    int rbase = m0 + (hk << 2);
    #pragma unroll
    for (int nt = 0; nt < 4; nt++) {
        int col = n0 + nt * 16 + lr;
        int b = col >> 10, p = col & 1023;
        #pragma unroll
        for (int j = 0; j < 4; j++) {
            int row = rbase + j;
            float v = acc[nt][j] + bias[row];
            size_t off = (size_t)b * (CH * HWPX) + (size_t)row * 1024 + p;
            Cf[off] = v + xres[off];
        }
    }
}

// ---------------- host launch ----------------
extern "C" void kernel_launch(void* const* d_in, const int* in_sizes, int n_in,
                              void* d_out, int out_size, void* d_ws, size_t ws_size,
                              hipStream_t stream)
{
    const float* x   = (const float*)d_in[0];
    const float* Wq  = (const float*)d_in[1];
    const float* bq  = (const float*)d_in[2];
    const float* Wk  = (const float*)d_in[3];
    const float* bk  = (const float*)d_in[4];
    const float* Wv  = (const float*)d_in[5];
    const float* bv  = (const float*)d_in[6];
    const float* Wo  = (const float*)d_in[7];
    const float* bo  = (const float*)d_in[8];
    const float* gqs = (const float*)d_in[9];
    const float* gqb = (const float*)d_in[10];
    const float* gks = (const float*)d_in[11];
    const float* gkb = (const float*)d_in[12];
    const float* gvs = (const float*)d_in[13];
    const float* gvb = (const float*)d_in[14];

    const size_t NEL  = (size_t)NB * HWPX * CH;   // 8388608
    const size_t F8B  = NEL;                      // fp8 buffers (8.4 MB)
    const size_t OB   = NEL * 2;                  // bf16 O buffer (16.8 MB)
    const size_t WTB  = 65536 * 2;                // Wt_o bf16
    const size_t W8B  = 768 * 256;                // fp8 weights
    const size_t BIASB = 4 * 256 * 4;
    size_t need = 4 * F8B + OB + WTB + W8B + BIASB;
    if (ws_size < need) return;

    char* w = (char*)d_ws;
    u8*   Xq8  = (u8*)(w);
    u8*   Qf8  = (u8*)(w + F8B);
    u8*   Kf8  = (u8*)(w + 2 * F8B);
    u8*   Vf8  = (u8*)(w + 3 * F8B);
    u16*  O    = (u16*)(w + 4 * F8B);
    u16*  Wt   = (u16*)(w + 4 * F8B + OB);
    u8*   W8   = (u8*)(w + 4 * F8B + OB + WTB);
    float* bias = (float*)(w + 4 * F8B + OB + WTB + W8B);

    wprep<<<dim3(1024), dim3(256), 0, stream>>>(Wq, bq, gqs, gqb, Wk, bk, gks, gkb,
                                                Wv, bv, gvs, gvb, Wo, bo, Wt, W8, bias);
    gn_kernel<<<dim3(1024), dim3(256), 0, stream>>>(x, Xq8);
    qkv_gemm<<<dim3(256, 6), dim3(256), 0, stream>>>(Xq8, W8, bias, Qf8, Kf8, Vf8);
    attn<<<dim3(256), dim3(512), 0, stream>>>(Qf8, Kf8, Vf8, O);
    gemm_out<<<dim3(512, 4), dim3(256), 0, stream>>>(Wt, O, bias + 768, (float*)d_out, x);
}